// Round 15
// baseline (1318.692 us; speedup 1.0000x reference)
//
#include <hip/hip_runtime.h>
#include <math.h>

constexpr int cB = 32, cCIN = 16, cT = 4096, cH = 192, cD = 4, cE = 4, cK = 7;
constexpr int cBANDS = 16, cP = 8, cHM = 384, cNCLS = 50, cBINS = 2049;
constexpr float cEPS = 1e-5f;
constexpr int TT = 64, HALO = 24;
constexpr int ZSTR = 112;      // zn row stride (u16): 224B, 16B-aligned
constexpr int NTAP = 19;
constexpr float INV_SQRT2 = 0.7071067811865475f;

typedef __bf16 bf16_t;
typedef bf16_t bf16x8 __attribute__((ext_vector_type(8)));
typedef float f32x4 __attribute__((ext_vector_type(4)));

// constexpr so unrolled indices FOLD (R5 lesson: __constant__ values can't fold -> scratch)
constexpr int OFFS[NTAP] = {-24,-16,-12,-8,-6,-4,-3,-2,-1,0,1,2,3,4,6,8,12,16,24};
constexpr int IDXT[cE][cK] = {
    {6, 7, 8, 9, 10, 11, 12},
    {4, 5, 7, 9, 11, 13, 14},
    {2, 3, 5, 9, 13, 15, 16},
    {0, 1, 3, 9, 15, 17, 18}};

__device__ __forceinline__ int xcd_swz(int bid) {
    // bijective for gridDim.x = 2048 (divisible by 8 XCDs)
    return (bid & 7) * 256 + (bid >> 3);
}

__device__ __forceinline__ float fast_erf(float x) {
    float ax = fabsf(x);
    float t = 1.0f / fmaf(0.3275911f, ax, 1.0f);
    float p = t * fmaf(t, fmaf(t, fmaf(t, fmaf(t, 1.061405429f, -1.453152027f),
                                       1.421413741f), -0.284496736f), 0.254829592f);
    float e = __expf(-ax * ax);
    float r = 1.0f - p * e;
    return copysignf(r, x);
}
__device__ __forceinline__ float gelu_exact(float v) {
    return 0.5f * v * (1.0f + fast_erf(v * INV_SQRT2));
}
__device__ __forceinline__ unsigned short f2bf(float f) {
    union { float f; unsigned u; } v; v.f = f;
    unsigned r = (v.u + 0x7FFFu + ((v.u >> 16) & 1u)) >> 16;
    return (unsigned short)r;
}
__device__ __forceinline__ float bf2f(unsigned short u) {
    union { unsigned u; float f; } v; v.u = ((unsigned)u) << 16;
    return v.f;
}
__device__ __forceinline__ float bflo(unsigned u) {
    union { unsigned u; float f; } v; v.u = u << 16;
    return v.f;
}
__device__ __forceinline__ float bfhi(unsigned u) {
    union { unsigned u; float f; } v; v.u = u & 0xFFFF0000u;
    return v.f;
}

// ---------------- zero scratch ----------------
__global__ __launch_bounds__(256) void k_zero(float* __restrict__ p, int n) {
    int i = blockIdx.x * 256 + threadIdx.x;
    if (i < n) p[i] = 0.f;
}

// ---------------- fp32 -> bf16 weight conversion ----------------
__global__ __launch_bounds__(256) void k_cvt(const float* __restrict__ src,
                                             unsigned short* __restrict__ dst, int n) {
    int i = blockIdx.x * 256 + threadIdx.x;
    if (i < n) dst[i] = f2bf(src[i]);
}

// ---------------- twiddle table ----------------
__global__ __launch_bounds__(256) void k_twiddle(float2* __restrict__ tw) {
    int ls = blockIdx.x;
    int n = cT >> ls;
    int cnt = n >> 1;
    int base = cT - (cT >> ls);
    for (int p = threadIdx.x; p < cnt; p += 256) {
        float ang = -6.283185307179586f * (float)p / (float)n;
        float sv, cv;
        sincosf(ang, &sv, &cv);
        tw[base + p] = make_float2(cv, sv);
    }
}

// ---------------- packed-real FFT magnitude: one block per (b, cin) ----------------
__global__ __launch_bounds__(256) void k_fft_mag(const float* __restrict__ x,
                                                 const float2* __restrict__ tw,
                                                 float* __restrict__ mag) {
    constexpr int N2 = cT / 2;   // 2048
    __shared__ float Sr[2][N2];
    __shared__ float Si[2][N2];
    int b = blockIdx.x / cCIN, c = blockIdx.x % cCIN;
    const float* xp = x + ((size_t)b * cCIN + c) * cT;
#pragma unroll
    for (int it = 0; it < N2 / 256; it++) {
        int t = threadIdx.x + it * 256;
        float2 v = *reinterpret_cast<const float2*>(&xp[2 * t]);
        Sr[0][t] = v.x; Si[0][t] = v.y;
    }
    __syncthreads();
    int cur = 0;
    for (int ls = 0; ls < 11; ls++) {
        int s = 1 << ls;
        int twb = cT - (cT >> (ls + 1));
#pragma unroll
        for (int it = 0; it < N2 / 512; it++) {
            int j = threadIdx.x + it * 256;
            int p = j >> ls;
            float2 w = tw[twb + p];
            float wr = w.x, wi = w.y;
            int ia = j, ib = j + N2 / 2;
            float ar = Sr[cur][ia], ai = Si[cur][ia];
            float br = Sr[cur][ib], bi = Si[cur][ib];
            int oa = j + (j & ~(s - 1));
            int ob = oa + s;
            Sr[cur ^ 1][oa] = ar + br;
            Si[cur ^ 1][oa] = ai + bi;
            float tr = ar - br, ti = ai - bi;
            Sr[cur ^ 1][ob] = tr * wr - ti * wi;
            Si[cur ^ 1][ob] = tr * wi + ti * wr;
        }
        __syncthreads();
        cur ^= 1;
    }
    const float scale = (1.0f / 64.0f) * (1.0f / 16.0f);
    for (int k = threadIdx.x; k <= N2; k += 256) {
        int k2 = k & (N2 - 1), km = (N2 - k) & (N2 - 1);
        float yr = Sr[cur][k2], yi = Si[cur][k2];
        float zr = Sr[cur][km], zi = Si[cur][km];
        float Ar = 0.5f * (yr + zr), Ai = 0.5f * (yi - zi);
        float Br = 0.5f * (yi + zi), Bi = -0.5f * (yr - zr);
        float wr, wi;
        if (k < N2) { float2 w = tw[k]; wr = w.x; wi = w.y; }
        else { wr = -1.f; wi = 0.f; }
        float Xr = Ar + wr * Br - wi * Bi;
        float Xi = Ai + wr * Bi + wi * Br;
        atomicAdd(&mag[b * cBINS + k], sqrtf(Xr * Xr + Xi * Xi) * scale);
    }
}

// ---------------- RBF basis ----------------
__global__ __launch_bounds__(256) void k_basis(float* __restrict__ basis) {
    __shared__ float vals[cBINS];
    __shared__ float red[256];
    int band = blockIdx.x;
    float cb = (float)band / 15.0f;
    float inv_w = 15.0f / 1.5f;
    float local = 0.f;
    for (int k = threadIdx.x; k < cBINS; k += 256) {
        float f = (float)k / 2048.0f;
        float u = (f - cb) * inv_w;
        float v = expf(-0.5f * u * u);
        vals[k] = v;
        local += v;
    }
    red[threadIdx.x] = local;
    __syncthreads();
    for (int s = 128; s > 0; s >>= 1) {
        if (threadIdx.x < s) red[threadIdx.x] += red[threadIdx.x + s];
        __syncthreads();
    }
    float inv_sum = 1.0f / fmaxf(red[0], 1e-8f);
    for (int k = threadIdx.x; k < cBINS; k += 256)
        basis[band * cBINS + k] = vals[k] * inv_sum;
}

// ---------------- summary ----------------
__global__ __launch_bounds__(256) void k_summary(const float* __restrict__ mag,
                                                 const float* __restrict__ basis,
                                                 float* __restrict__ summary) {
    int b = blockIdx.x;
    float acc[cBANDS];
#pragma unroll
    for (int i = 0; i < cBANDS; i++) acc[i] = 0.f;
    for (int k = threadIdx.x; k < cBINS; k += 256) {
        float lm = log1pf(mag[b * cBINS + k]);
#pragma unroll
        for (int band = 0; band < cBANDS; band++) acc[band] += lm * basis[band * cBINS + k];
    }
    __shared__ float red[cBANDS][256];
#pragma unroll
    for (int band = 0; band < cBANDS; band++) red[band][threadIdx.x] = acc[band];
    __syncthreads();
    for (int s = 128; s > 0; s >>= 1) {
        if (threadIdx.x < s)
#pragma unroll
            for (int band = 0; band < cBANDS; band++)
                red[band][threadIdx.x] += red[band][threadIdx.x + s];
        __syncthreads();
    }
    if (threadIdx.x < cBANDS) summary[b * cBANDS + threadIdx.x] = red[threadIdx.x][0];
}

// ---------------- router: LN/proj/prototypes/softmax + routes + assign (cheap part only) ----------------
__global__ __launch_bounds__(64) void k_router(
    const float* __restrict__ summary, const float* __restrict__ ln_g,
    const float* __restrict__ ln_b, const float* __restrict__ proj_w,
    const float* __restrict__ prototypes, const float* __restrict__ route_lib,
    float* __restrict__ routes, float* __restrict__ assign_out) {
    int b = threadIdx.x;
    if (b >= cB) return;
    float s[cBANDS];
    float mean = 0.f;
#pragma unroll
    for (int i = 0; i < cBANDS; i++) { s[i] = summary[b * cBANDS + i]; mean += s[i]; }
    mean *= (1.0f / cBANDS);
    float var = 0.f;
#pragma unroll
    for (int i = 0; i < cBANDS; i++) { float d = s[i] - mean; var += d * d; }
    var *= (1.0f / cBANDS);
    float rstd = rsqrtf(var + cEPS);
#pragma unroll
    for (int i = 0; i < cBANDS; i++) s[i] = (s[i] - mean) * rstd * ln_g[i] + ln_b[i];
    float rs[cBANDS];
#pragma unroll
    for (int j = 0; j < cBANDS; j++) {
        float a = 0.f;
#pragma unroll
        for (int i = 0; i < cBANDS; i++) a += s[i] * proj_w[j * cBANDS + i];
        rs[j] = a;
    }
    float logits[cP];
    float mx = -1e30f;
#pragma unroll
    for (int p = 0; p < cP; p++) {
        float a = 0.f;
#pragma unroll
        for (int j = 0; j < cBANDS; j++) {
            float d = rs[j] - prototypes[p * cBANDS + j];
            a += d * d;
        }
        logits[p] = -(a * (1.0f / cBANDS)) * 4.0f;
        mx = fmaxf(mx, logits[p]);
    }
    float assign[cP];
    float denom = 0.f;
#pragma unroll
    for (int p = 0; p < cP; p++) { assign[p] = expf(logits[p] - mx); denom += assign[p]; }
    float invden = 1.0f / denom;
#pragma unroll
    for (int p = 0; p < cP; p++) {
        assign[p] *= invden;
        assign_out[b * cP + p] = assign[p];
    }
    for (int d = 0; d < cD; d++) {
        float r[cE];
        float rmx = -1e30f;
#pragma unroll
        for (int e = 0; e < cE; e++) {
            float a = 0.f;
#pragma unroll
            for (int p = 0; p < cP; p++) a += assign[p] * route_lib[(p * cD + d) * cE + e];
            r[e] = a;
            rmx = fmaxf(rmx, a);
        }
        float rden = 0.f;
#pragma unroll
        for (int e = 0; e < cE; e++) { r[e] = expf(r[e] - rmx); rden += r[e]; }
        float rinv = 1.0f / rden;
#pragma unroll
        for (int e = 0; e < cE; e++) routes[(b * cD + d) * cE + e] = r[e] * rinv;
    }
}

// ---------------- gains: one thread per (b, d, c), coalesced over gain_lib ----------------
__global__ __launch_bounds__(256) void k_gains(const float* __restrict__ assign,
                                               const float* __restrict__ gain_lib,
                                               float* __restrict__ gains) {
    int i = blockIdx.x * 256 + threadIdx.x;
    if (i >= cB * cD * cH) return;
    int b = i / (cD * cH);
    int dc = i % (cD * cH);            // d*cH + c
    float a = 0.f;
#pragma unroll
    for (int p = 0; p < cP; p++) a += assign[b * cP + p] * gain_lib[p * cD * cH + dc];
    gains[i] = 1.0f + 0.5f * tanhf(a);
}

// ---------------- effective 19-tap conv weights ----------------
__global__ __launch_bounds__(192) void k_weff(const float* __restrict__ ew_all,
                                              const float* __restrict__ routes,
                                              unsigned short* __restrict__ weff_g) {
    int bd = blockIdx.x;
    int d = bd % cD;
    int c = threadIdx.x;
    float rte[cE];
#pragma unroll
    for (int e = 0; e < cE; e++) rte[e] = routes[bd * cE + e];
    float acc[NTAP];
#pragma unroll
    for (int o = 0; o < NTAP; o++) acc[o] = 0.f;
#pragma unroll
    for (int e = 0; e < cE; e++) {
#pragma unroll
        for (int k = 0; k < cK; k++)
            acc[IDXT[e][k]] += rte[e] * ew_all[(((size_t)d * cE + e) * cH + c) * cK + k];
    }
    unsigned short* dst = weff_g + ((size_t)bd * cH + c) * 20;
#pragma unroll
    for (int o = 0; o < NTAP; o++) dst[o] = f2bf(acc[o]);
    dst[NTAP] = 0;
}

// ---------------- stem (writes bf16 z) ----------------
constexpr int STT = 256;
__global__ __launch_bounds__(256) void k_stem(const float* __restrict__ x,
                                              const float* __restrict__ stem_w,
                                              const float* __restrict__ bn_g,
                                              const float* __restrict__ bn_b,
                                              unsigned short* __restrict__ z,
                                              float* __restrict__ sums_out) {
    __shared__ float xs[cCIN][STT + 2];
    __shared__ float ws[cH * cCIN * 3];
    int blk = blockIdx.x;
    int b = blk / (cT / STT);
    int t0 = (blk % (cT / STT)) * STT;
    for (int i = threadIdx.x; i < cH * cCIN * 3; i += 256) ws[i] = stem_w[i];
    for (int i = threadIdx.x; i < cCIN * (STT + 2); i += 256) {
        int c = i / (STT + 2), tt = i % (STT + 2);
        int gt = t0 + tt - 1;
        xs[c][tt] = (gt >= 0 && gt < cT) ? x[((size_t)b * cCIN + c) * cT + gt] : 0.f;
    }
    __syncthreads();
    int tt = threadIdx.x;
    float xv[cCIN][3];
#pragma unroll
    for (int c = 0; c < cCIN; c++)
#pragma unroll
        for (int k = 0; k < 3; k++) xv[c][k] = xs[c][tt + k];
    int gt = t0 + tt;
    float bnrs = rsqrtf(1.0f + cEPS);
    float s = 0.f, q = 0.f;
    for (int h = 0; h < cH; h++) {
        const float* w = &ws[h * cCIN * 3];
        float acc = 0.f;
#pragma unroll
        for (int c = 0; c < cCIN; c++)
#pragma unroll
            for (int k = 0; k < 3; k++) acc += xv[c][k] * w[c * 3 + k];
        float v = acc * (bn_g[h] * bnrs) + bn_b[h];
        unsigned short rb = f2bf(gelu_exact(v));
        float res = bf2f(rb);
        z[((size_t)b * cH + h) * cT + gt] = rb;
        s += res; q += res * res;
    }
#pragma unroll
    for (int off = 32; off > 0; off >>= 1) { s += __shfl_down(s, off); q += __shfl_down(q, off); }
    if ((threadIdx.x & 63) == 0) {
        atomicAdd(&sums_out[b * 2], s);
        atomicAdd(&sums_out[b * 2 + 1], q);
    }
}

// ---------------- block part 1 (bf16 z stream) ----------------
__global__ __launch_bounds__(256, 2) void k_block1(
    const unsigned short* __restrict__ zin, unsigned short* __restrict__ zout,
    const float* __restrict__ sums_in, float* __restrict__ sums_out,
    const float* __restrict__ g1, const float* __restrict__ b1,
    const unsigned short* __restrict__ weff_g, const unsigned short* __restrict__ mwb,
    const float* __restrict__ mg, const float* __restrict__ mb,
    const float* __restrict__ gains, int d) {
    __shared__ unsigned short zn[cH][ZSTR];
    __shared__ unsigned short mxT[TT][200];
    int blk = xcd_swz(blockIdx.x);
    int b = blk / (cT / TT);
    int t0 = (blk % (cT / TT)) * TT;
    int tid = threadIdx.x;
    const float invN = 1.0f / (float)(cH * cT);
    float mean = sums_in[b * 2] * invN;
    float var = sums_in[b * 2 + 1] * invN - mean * mean;
    float rstd = rsqrtf(var + cEPS);
    // stage normalized tile with halo — fully unrolled; interior fast path (MLP: 21 8B loads)
    constexpr int S_ITERS = cH * 28 / 256;   // 21
    bool interior = (t0 >= HALO) && (t0 + TT + HALO <= cT);
    if (interior) {
#pragma unroll
        for (int it = 0; it < S_ITERS; it++) {
            int i = tid + it * 256;
            int c = i / 28, tt = (i % 28) * 4;
            int gt = t0 + tt - HALO;
            float gc = g1[c], bc = b1[c];
            ushort4 v = *reinterpret_cast<const ushort4*>(&zin[((size_t)b * cH + c) * cT + gt]);
            ushort4 pk;
            pk.x = f2bf((bf2f(v.x) - mean) * rstd * gc + bc);
            pk.y = f2bf((bf2f(v.y) - mean) * rstd * gc + bc);
            pk.z = f2bf((bf2f(v.z) - mean) * rstd * gc + bc);
            pk.w = f2bf((bf2f(v.w) - mean) * rstd * gc + bc);
            *reinterpret_cast<ushort4*>(&zn[c][tt]) = pk;
        }
    } else {
#pragma unroll
        for (int it = 0; it < S_ITERS; it++) {
            int i = tid + it * 256;
            int c = i / 28, tt = (i % 28) * 4;
            int gt = t0 + tt - HALO;
            float gc = g1[c], bc = b1[c];
            const unsigned short* zp = &zin[((size_t)b * cH + c) * cT];
            float n0 = (gt + 0 >= 0 && gt + 0 < cT) ? (bf2f(zp[gt + 0]) - mean) * rstd * gc + bc : 0.f;
            float n1 = (gt + 1 >= 0 && gt + 1 < cT) ? (bf2f(zp[gt + 1]) - mean) * rstd * gc + bc : 0.f;
            float n2 = (gt + 2 >= 0 && gt + 2 < cT) ? (bf2f(zp[gt + 2]) - mean) * rstd * gc + bc : 0.f;
            float n3 = (gt + 3 >= 0 && gt + 3 < cT) ? (bf2f(zp[gt + 3]) - mean) * rstd * gc + bc : 0.f;
            ushort4 pk;
            pk.x = f2bf(n0); pk.y = f2bf(n1); pk.z = f2bf(n2); pk.w = f2bf(n3);
            *reinterpret_cast<ushort4*>(&zn[c][tt]) = pk;
        }
    }
    // residual prefetch issued EARLY (T14)
    int lane = tid & 63, wid = tid >> 6;
    int lrow = lane & 15;
    int lk8 = (lane >> 4) << 3;
    int r0 = (lane >> 4) << 2;
    int mbase = wid * 48;
    float res[3][4][4];
#pragma unroll
    for (int mt = 0; mt < 3; mt++)
#pragma unroll
        for (int nt = 0; nt < 4; nt++)
#pragma unroll
            for (int r = 0; r < 4; r++)
                res[mt][nt][r] = bf2f(zin[((size_t)b * cH + mbase + mt * 16 + r0 + r) * cT +
                                         t0 + nt * 16 + lrow]);
    __syncthreads();
    // dwconv: lane owns one channel; window in registers, all-static indices
    if (tid < cH) {
        int c = tid;
        const unsigned short* wp = weff_g + ((size_t)(b * cD + d) * cH + c) * 20;
        float wv[NTAP];
#pragma unroll
        for (int o = 0; o < NTAP; o++) wv[o] = bf2f(wp[o]);
        float g = gains[((size_t)b * cD + d) * cH + c];
        float win[ZSTR];
#pragma unroll
        for (int v = 0; v < 14; v++) {
            bf16x8 w8 = *reinterpret_cast<const bf16x8*>(&zn[c][8 * v]);
#pragma unroll
            for (int u = 0; u < 8; u++) win[8 * v + u] = (float)w8[u];
        }
#pragma unroll
        for (int t = 0; t < TT; t++) {
            float a = 0.f;
#pragma unroll
            for (int o = 0; o < NTAP; o++)
                a = fmaf(wv[o], win[t + HALO + OFFS[o]], a);
            mxT[t][c] = f2bf(a * g);
        }
    }
    __syncthreads();
    // mix matmul: M=192, K=192, N=64
    f32x4 acc[3][4];
#pragma unroll
    for (int mt = 0; mt < 3; mt++)
#pragma unroll
        for (int nt = 0; nt < 4; nt++)
#pragma unroll
            for (int r = 0; r < 4; r++) acc[mt][nt][r] = 0.f;
#pragma unroll
    for (int kk = 0; kk < 6; kk++) {
        int k0 = kk * 32 + lk8;
        bf16x8 a0 = *reinterpret_cast<const bf16x8*>(&mwb[(size_t)(mbase + lrow) * cH + k0]);
        bf16x8 a1 = *reinterpret_cast<const bf16x8*>(&mwb[(size_t)(mbase + 16 + lrow) * cH + k0]);
        bf16x8 a2 = *reinterpret_cast<const bf16x8*>(&mwb[(size_t)(mbase + 32 + lrow) * cH + k0]);
#pragma unroll
        for (int nt = 0; nt < 4; nt++) {
            bf16x8 bf = *reinterpret_cast<const bf16x8*>(&mxT[nt * 16 + lrow][k0]);
            acc[0][nt] = __builtin_amdgcn_mfma_f32_16x16x32_bf16(a0, bf, acc[0][nt], 0, 0, 0);
            acc[1][nt] = __builtin_amdgcn_mfma_f32_16x16x32_bf16(a1, bf, acc[1][nt], 0, 0, 0);
            acc[2][nt] = __builtin_amdgcn_mfma_f32_16x16x32_bf16(a2, bf, acc[2][nt], 0, 0, 0);
        }
    }
    float bnrs = rsqrtf(1.0f + cEPS);
    float s = 0.f, q = 0.f;
#pragma unroll
    for (int mt = 0; mt < 3; mt++) {
#pragma unroll
        for (int nt = 0; nt < 4; nt++) {
#pragma unroll
            for (int r = 0; r < 4; r++) {
                int o = mbase + mt * 16 + r0 + r;
                int t = t0 + nt * 16 + lrow;
                size_t idx = ((size_t)b * cH + o) * cT + t;
                unsigned short vb = f2bf(res[mt][nt][r] +
                                         gelu_exact(acc[mt][nt][r] * (mg[o] * bnrs) + mb[o]));
                float val = bf2f(vb);
                zout[idx] = vb;
                s += val; q += val * val;
            }
        }
    }
#pragma unroll
    for (int off = 32; off > 0; off >>= 1) { s += __shfl_down(s, off); q += __shfl_down(q, off); }
    if (lane == 0) {
        atomicAdd(&sums_out[b * 2], s);
        atomicAdd(&sums_out[b * 2 + 1], q);
    }
}

// ---------------- block part 2: 512 threads / 8 waves, 2 barriers ----------------
// launch_bounds(512, 2): declared 1 block/CU -> VGPR cap 256, allocator free (~110-125 natural).
// HW still co-schedules 2 blocks/CU at runtime if VGPR<=128 & LDS 75.8Kx2<=160K -> 4 waves/SIMD.
// (R14's launch_bounds(512) defaulted to a 64-VGPR cap -> spill; R8/R11: declared caps spill.)
__global__ __launch_bounds__(512, 2) void k_block2(
    unsigned short* __restrict__ z, const float* __restrict__ sums_in,
    float* __restrict__ sums_out,
    const float* __restrict__ g2, const float* __restrict__ b2,
    const unsigned short* __restrict__ w1b, const float* __restrict__ bb1,
    const unsigned short* __restrict__ w2b, const float* __restrict__ bb2) {
    __shared__ unsigned short znT[TT][200];   // 25.6K
    __shared__ unsigned short hT[TT][392];    // 50.2K, 784B rows (49x16B, odd slot stride)
    int blk = xcd_swz(blockIdx.x);
    int b = blk / (cT / TT);
    int t0 = (blk % (cT / TT)) * TT;
    const float invN = 1.0f / (float)(cH * cT);
    float mean = sums_in[b * 2] * invN;
    float var = sums_in[b * 2 + 1] * invN - mean * mean;
    float rstd = rsqrtf(var + cEPS);
    // staging — fully unrolled (6 8B loads per thread at 512 threads)
    constexpr int S_ITERS = cH * (TT / 4) / 512;  // 6
#pragma unroll
    for (int it = 0; it < S_ITERS; it++) {
        int i = threadIdx.x + it * 512;
        int c = i >> 4, t4 = (i & 15) << 2;
        ushort4 v = *reinterpret_cast<const ushort4*>(&z[((size_t)b * cH + c) * cT + t0 + t4]);
        float gc = g2[c], bc = b2[c];
        znT[t4 + 0][c] = f2bf((bf2f(v.x) - mean) * rstd * gc + bc);
        znT[t4 + 1][c] = f2bf((bf2f(v.y) - mean) * rstd * gc + bc);
        znT[t4 + 2][c] = f2bf((bf2f(v.z) - mean) * rstd * gc + bc);
        znT[t4 + 3][c] = f2bf((bf2f(v.w) - mean) * rstd * gc + bc);
    }
    int lane = threadIdx.x & 63, wid = threadIdx.x >> 6;  // wid 0..7
    int lrow = lane & 15;
    int lk8 = (lane >> 4) << 3;
    int r0 = (lane >> 4) << 2;
    int mg = wid >> 1, ng = wid & 1;   // w2 role: M-group (48 rows), N-group (32 t's)
    int obase = mg * 48;
    int tb = ng * 32;
    // residual prefetch (T14) — wave's w2 output block
    float res[3][2][4];
#pragma unroll
    for (int mt = 0; mt < 3; mt++)
#pragma unroll
        for (int nt = 0; nt < 2; nt++)
#pragma unroll
            for (int r = 0; r < 4; r++)
                res[mt][nt][r] = bf2f(z[((size_t)b * cH + obase + mt * 16 + r0 + r) * cT +
                                        t0 + tb + nt * 16 + lrow]);
    __syncthreads();   // A: znT ready
    // ---- w1: wave owns rows [wid*48, wid*48+48), all 64 t ----
    int w1base = wid * 48;
    f32x4 acc1[3][4];
#pragma unroll
    for (int mt = 0; mt < 3; mt++) {
#pragma unroll
        for (int r = 0; r < 4; r++) {
            float bv = bb1[w1base + mt * 16 + r0 + r];
            acc1[mt][0][r] = bv; acc1[mt][1][r] = bv; acc1[mt][2][r] = bv; acc1[mt][3][r] = bv;
        }
    }
#pragma unroll
    for (int kk = 0; kk < 6; kk++) {
        int k0 = kk * 32 + lk8;
        bf16x8 a0 = *reinterpret_cast<const bf16x8*>(&w1b[(size_t)(w1base + lrow) * cH + k0]);
        bf16x8 a1 = *reinterpret_cast<const bf16x8*>(&w1b[(size_t)(w1base + 16 + lrow) * cH + k0]);
        bf16x8 a2 = *reinterpret_cast<const bf16x8*>(&w1b[(size_t)(w1base + 32 + lrow) * cH + k0]);
#pragma unroll
        for (int nt = 0; nt < 4; nt++) {
            bf16x8 bf = *reinterpret_cast<const bf16x8*>(&znT[nt * 16 + lrow][k0]);
            acc1[0][nt] = __builtin_amdgcn_mfma_f32_16x16x32_bf16(a0, bf, acc1[0][nt], 0, 0, 0);
            acc1[1][nt] = __builtin_amdgcn_mfma_f32_16x16x32_bf16(a1, bf, acc1[1][nt], 0, 0, 0);
            acc1[2][nt] = __builtin_amdgcn_mfma_f32_16x16x32_bf16(a2, bf, acc1[2][nt], 0, 0, 0);
        }
    }
    // write hT (cols = wave's hidden rows)
#pragma unroll
    for (int mt = 0; mt < 3; mt++) {
        int o0 = w1base + mt * 16 + r0;
#pragma unroll
        for (int nt = 0; nt < 4; nt++) {
            int t = nt * 16 + lrow;
            ushort4 pk;
            pk.x = f2bf(gelu_exact(acc1[mt][nt][0]));
            pk.y = f2bf(gelu_exact(acc1[mt][nt][1]));
            pk.z = f2bf(gelu_exact(acc1[mt][nt][2]));
            pk.w = f2bf(gelu_exact(acc1[mt][nt][3]));
            *reinterpret_cast<ushort4*>(&hT[t][o0]) = pk;
        }
    }
    __syncthreads();   // B: hT ready
    // ---- w2: K=384 full; wave computes rows obase, t in [tb, tb+32) ----
    f32x4 acc2[3][2];
#pragma unroll
    for (int mt = 0; mt < 3; mt++) {
#pragma unroll
        for (int r = 0; r < 4; r++) {
            float bv = bb2[obase + mt * 16 + r0 + r];
            acc2[mt][0][r] = bv; acc2[mt][1][r] = bv;
        }
    }
#pragma unroll
    for (int kk = 0; kk < 12; kk++) {
        int k0 = kk * 32 + lk8;
        bf16x8 a0 = *reinterpret_cast<const bf16x8*>(&w2b[(size_t)(obase + lrow) * cHM + k0]);
        bf16x8 a1 = *reinterpret_cast<const bf16x8*>(&w2b[(size_t)(obase + 16 + lrow) * cHM + k0]);
        bf16x8 a2 = *reinterpret_cast<const bf16x8*>(&w2b[(size_t)(obase + 32 + lrow) * cHM + k0]);
#pragma unroll
        for (int nt = 0; nt < 2; nt++) {
            bf16x8 bf = *reinterpret_cast<const bf16x8*>(&hT[tb + nt * 16 + lrow][k0]);
            acc2[0][nt] = __builtin_amdgcn_mfma_f32_16x16x32_bf16(a0, bf, acc2[0][nt], 0, 0, 0);
            acc2[1][nt] = __builtin_amdgcn_mfma_f32_16x16x32_bf16(a1, bf, acc2[1][nt], 0, 0, 0);
            acc2[2][nt] = __builtin_amdgcn_mfma_f32_16x16x32_bf16(a2, bf, acc2[2][nt], 0, 0, 0);
        }
    }
    float s = 0.f, q = 0.f;
#pragma unroll
    for (int mt = 0; mt < 3; mt++) {
#pragma unroll
        for (int nt = 0; nt < 2; nt++) {
#pragma unroll
            for (int r = 0; r < 4; r++) {
                int o = obase + mt * 16 + r0 + r;
                int t = t0 + tb + nt * 16 + lrow;
                size_t idx = ((size_t)b * cH + o) * cT + t;
                unsigned short vb = f2bf(res[mt][nt][r] + acc2[mt][nt][r]);
                float val = bf2f(vb);
                z[idx] = vb;
                s += val; q += val * val;
            }
        }
    }
#pragma unroll
    for (int off = 32; off > 0; off >>= 1) { s += __shfl_down(s, off); q += __shfl_down(q, off); }
    if (lane == 0) {
        atomicAdd(&sums_out[b * 2], s);
        atomicAdd(&sums_out[b * 2 + 1], q);
    }
}

// ---------------- global average pool (bf16 z) ----------------
__global__ __launch_bounds__(256) void k_pool(const unsigned short* __restrict__ z,
                                              float* __restrict__ pooled) {
    int bh = blockIdx.x;
    const unsigned short* zp = z + (size_t)bh * cT;
    float s = 0.f;
#pragma unroll
    for (int it = 0; it < 2; it++) {
        uint4 v = *reinterpret_cast<const uint4*>(&zp[(threadIdx.x + it * 256) * 8]);
        s += bflo(v.x) + bfhi(v.x) + bflo(v.y) + bfhi(v.y) +
             bflo(v.z) + bfhi(v.z) + bflo(v.w) + bfhi(v.w);
    }
    __shared__ float red[256];
    red[threadIdx.x] = s;
    __syncthreads();
    for (int st = 128; st > 0; st >>= 1) {
        if (threadIdx.x < st) red[threadIdx.x] += red[threadIdx.x + st];
        __syncthreads();
    }
    if (threadIdx.x == 0) pooled[bh] = red[0] * (1.0f / cT);
}

// ---------------- head ----------------
__global__ __launch_bounds__(256) void k_head(const float* __restrict__ pooled,
                                              const float* __restrict__ hw,
                                              const float* __restrict__ hb,
                                              float* __restrict__ out) {
    int i = blockIdx.x * 256 + threadIdx.x;
    if (i >= cB * cNCLS) return;
    int b = i / cNCLS, n = i % cNCLS;
    float acc = hb[n];
    const float* pw = pooled + b * cH;
    const float* wr = hw + n * cH;
    for (int h = 0; h < cH; h++) acc += pw[h] * wr[h];
    out[i] = acc;
}

extern "C" void kernel_launch(void* const* d_in, const int* in_sizes, int n_in,
                              void* d_out, int out_size, void* d_ws, size_t ws_size,
                              hipStream_t stream) {
    const float* x          = (const float*)d_in[0];
    const float* stem_w     = (const float*)d_in[1];
    const float* stem_bn_g  = (const float*)d_in[2];
    const float* stem_bn_b  = (const float*)d_in[3];
    const float* ln_g       = (const float*)d_in[4];
    const float* ln_b       = (const float*)d_in[5];
    const float* proj_w     = (const float*)d_in[6];
    const float* prototypes = (const float*)d_in[7];
    const float* route_lib  = (const float*)d_in[8];
    const float* gain_lib   = (const float*)d_in[9];
    const float* norm1_g    = (const float*)d_in[10];
    const float* norm1_b    = (const float*)d_in[11];
    const float* expert_w   = (const float*)d_in[12];
    const float* mix_w      = (const float*)d_in[13];
    const float* mix_bn_g   = (const float*)d_in[14];
    const float* mix_bn_b   = (const float*)d_in[15];
    const float* norm2_g    = (const float*)d_in[16];
    const float* norm2_b    = (const float*)d_in[17];
    const float* mlp_w1     = (const float*)d_in[18];
    const float* mlp_b1     = (const float*)d_in[19];
    const float* mlp_w2     = (const float*)d_in[20];
    const float* mlp_b2     = (const float*)d_in[21];
    const float* head_w     = (const float*)d_in[22];
    const float* head_b     = (const float*)d_in[23];

    float* ws = (float*)d_ws;
    size_t off = 0;
    const size_t ZN = (size_t)cB * cH * cT;
    unsigned short* zA = (unsigned short*)(ws + off); off += ZN / 2;   // bf16 z stream
    unsigned short* zB = (unsigned short*)(ws + off); off += ZN / 2;
    float* mag     = ws + off; off += (size_t)cB * cBINS;
    float* sums    = ws + off; off += 9 * cB * 2;
    float* basis   = ws + off; off += (size_t)cBANDS * cBINS;
    float* summary = ws + off; off += cB * cBANDS;
    float* routes  = ws + off; off += cB * cD * cE;
    float* assign  = ws + off; off += cB * cP;
    float* gains   = ws + off; off += (size_t)cB * cD * cH;
    float* pooled  = ws + off; off += cB * cH;
    float2* tw     = (float2*)(ws + off); off += 2 * (cT - 1) + 2;
    unsigned short* mixb = (unsigned short*)(ws + off); off += (size_t)cD * cH * cH / 2;
    unsigned short* w1b  = (unsigned short*)(ws + off); off += (size_t)cD * cHM * cH / 2;
    unsigned short* w2b  = (unsigned short*)(ws + off); off += (size_t)cD * cH * cHM / 2;
    unsigned short* weff = (unsigned short*)(ws + off); off += (size_t)cB * cD * cH * 20 / 2;

    int nz = cB * cBINS + 9 * cB * 2;
    k_zero<<<(nz + 255) / 256, 256, 0, stream>>>(mag, nz);

    k_cvt<<<(cD * cH * cH + 255) / 256, 256, 0, stream>>>(mix_w, mixb, cD * cH * cH);
    k_cvt<<<(cD * cHM * cH + 255) / 256, 256, 0, stream>>>(mlp_w1, w1b, cD * cHM * cH);
    k_cvt<<<(cD * cH * cHM + 255) / 256, 256, 0, stream>>>(mlp_w2, w2b, cD * cH * cHM);

    k_twiddle<<<12, 256, 0, stream>>>(tw);
    k_fft_mag<<<cB * cCIN, 256, 0, stream>>>(x, tw, mag);
    k_basis<<<cBANDS, 256, 0, stream>>>(basis);
    k_summary<<<cB, 256, 0, stream>>>(mag, basis, summary);
    k_router<<<1, 64, 0, stream>>>(summary, ln_g, ln_b, proj_w, prototypes,
                                   route_lib, routes, assign);
    k_gains<<<(cB * cD * cH + 255) / 256, 256, 0, stream>>>(assign, gain_lib, gains);
    k_weff<<<cB * cD, 192, 0, stream>>>(expert_w, routes, weff);

    k_stem<<<cB * (cT / STT), 256, 0, stream>>>(x, stem_w, stem_bn_g, stem_bn_b, zA,
                                                sums + 0 * cB * 2);

    unsigned short* zi = zA;
    unsigned short* zo = zB;
    for (int d = 0; d < cD; d++) {
        k_block1<<<cB * (cT / TT), 256, 0, stream>>>(
            zi, zo, sums + (size_t)(2 * d) * cB * 2, sums + (size_t)(2 * d + 1) * cB * 2,
            norm1_g + d * cH, norm1_b + d * cH,
            weff, mixb + (size_t)d * cH * cH,
            mix_bn_g + d * cH, mix_bn_b + d * cH, gains, d);
        k_block2<<<cB * (cT / TT), 512, 0, stream>>>(
            zo, sums + (size_t)(2 * d + 1) * cB * 2, sums + (size_t)(2 * d + 2) * cB * 2,
            norm2_g + d * cH, norm2_b + d * cH,
            w1b + (size_t)d * cHM * cH, mlp_b1 + d * cHM,
            w2b + (size_t)d * cH * cHM, mlp_b2 + d * cH);
        unsigned short* t = zi; zi = zo; zo = t;
    }

    k_pool<<<cB * cH, 256, 0, stream>>>(zi, pooled);
    k_head<<<(cB * cNCLS + 255) / 256, 256, 0, stream>>>(pooled, head_w, head_b,
                                                         (float*)d_out);
}

// Round 16
// 1041.876 us; speedup vs baseline: 1.2657x; 1.2657x over previous
//
#include <hip/hip_runtime.h>
#include <math.h>

constexpr int cB = 32, cCIN = 16, cT = 4096, cH = 192, cD = 4, cE = 4, cK = 7;
constexpr int cBANDS = 16, cP = 8, cHM = 384, cNCLS = 50, cBINS = 2049;
constexpr float cEPS = 1e-5f;
constexpr int TT = 64, HALO = 24;
constexpr int ZSTR = 112;      // zn row stride (u16): 224B, 16B-aligned
constexpr int NTAP = 19;
constexpr float INV_SQRT2 = 0.7071067811865475f;

typedef __bf16 bf16_t;
typedef bf16_t bf16x8 __attribute__((ext_vector_type(8)));
typedef float f32x4 __attribute__((ext_vector_type(4)));

// constexpr so unrolled indices FOLD (R5 lesson: __constant__ values can't fold -> scratch)
constexpr int OFFS[NTAP] = {-24,-16,-12,-8,-6,-4,-3,-2,-1,0,1,2,3,4,6,8,12,16,24};
constexpr int IDXT[cE][cK] = {
    {6, 7, 8, 9, 10, 11, 12},
    {4, 5, 7, 9, 11, 13, 14},
    {2, 3, 5, 9, 13, 15, 16},
    {0, 1, 3, 9, 15, 17, 18}};

__device__ __forceinline__ int xcd_swz(int bid) {
    // bijective for gridDim.x = 2048 (divisible by 8 XCDs)
    return (bid & 7) * 256 + (bid >> 3);
}

__device__ __forceinline__ float fast_erf(float x) {
    float ax = fabsf(x);
    float t = 1.0f / fmaf(0.3275911f, ax, 1.0f);
    float p = t * fmaf(t, fmaf(t, fmaf(t, fmaf(t, 1.061405429f, -1.453152027f),
                                       1.421413741f), -0.284496736f), 0.254829592f);
    float e = __expf(-ax * ax);
    float r = 1.0f - p * e;
    return copysignf(r, x);
}
__device__ __forceinline__ float gelu_exact(float v) {
    return 0.5f * v * (1.0f + fast_erf(v * INV_SQRT2));
}
__device__ __forceinline__ unsigned short f2bf(float f) {
    union { float f; unsigned u; } v; v.f = f;
    unsigned r = (v.u + 0x7FFFu + ((v.u >> 16) & 1u)) >> 16;
    return (unsigned short)r;
}
__device__ __forceinline__ float bf2f(unsigned short u) {
    union { unsigned u; float f; } v; v.u = ((unsigned)u) << 16;
    return v.f;
}
__device__ __forceinline__ float bflo(unsigned u) {
    union { unsigned u; float f; } v; v.u = u << 16;
    return v.f;
}
__device__ __forceinline__ float bfhi(unsigned u) {
    union { unsigned u; float f; } v; v.u = u & 0xFFFF0000u;
    return v.f;
}

// ---------------- zero scratch ----------------
__global__ __launch_bounds__(256) void k_zero(float* __restrict__ p, int n) {
    int i = blockIdx.x * 256 + threadIdx.x;
    if (i < n) p[i] = 0.f;
}

// ---------------- fp32 -> bf16 weight conversion ----------------
__global__ __launch_bounds__(256) void k_cvt(const float* __restrict__ src,
                                             unsigned short* __restrict__ dst, int n) {
    int i = blockIdx.x * 256 + threadIdx.x;
    if (i < n) dst[i] = f2bf(src[i]);
}

// ---------------- twiddle table ----------------
__global__ __launch_bounds__(256) void k_twiddle(float2* __restrict__ tw) {
    int ls = blockIdx.x;
    int n = cT >> ls;
    int cnt = n >> 1;
    int base = cT - (cT >> ls);
    for (int p = threadIdx.x; p < cnt; p += 256) {
        float ang = -6.283185307179586f * (float)p / (float)n;
        float sv, cv;
        sincosf(ang, &sv, &cv);
        tw[base + p] = make_float2(cv, sv);
    }
}

// ---------------- packed-real FFT magnitude: one block per (b, cin) ----------------
__global__ __launch_bounds__(256) void k_fft_mag(const float* __restrict__ x,
                                                 const float2* __restrict__ tw,
                                                 float* __restrict__ mag) {
    constexpr int N2 = cT / 2;   // 2048
    __shared__ float Sr[2][N2];
    __shared__ float Si[2][N2];
    int b = blockIdx.x / cCIN, c = blockIdx.x % cCIN;
    const float* xp = x + ((size_t)b * cCIN + c) * cT;
#pragma unroll
    for (int it = 0; it < N2 / 256; it++) {
        int t = threadIdx.x + it * 256;
        float2 v = *reinterpret_cast<const float2*>(&xp[2 * t]);
        Sr[0][t] = v.x; Si[0][t] = v.y;
    }
    __syncthreads();
    int cur = 0;
    for (int ls = 0; ls < 11; ls++) {
        int s = 1 << ls;
        int twb = cT - (cT >> (ls + 1));
#pragma unroll
        for (int it = 0; it < N2 / 512; it++) {
            int j = threadIdx.x + it * 256;
            int p = j >> ls;
            float2 w = tw[twb + p];
            float wr = w.x, wi = w.y;
            int ia = j, ib = j + N2 / 2;
            float ar = Sr[cur][ia], ai = Si[cur][ia];
            float br = Sr[cur][ib], bi = Si[cur][ib];
            int oa = j + (j & ~(s - 1));
            int ob = oa + s;
            Sr[cur ^ 1][oa] = ar + br;
            Si[cur ^ 1][oa] = ai + bi;
            float tr = ar - br, ti = ai - bi;
            Sr[cur ^ 1][ob] = tr * wr - ti * wi;
            Si[cur ^ 1][ob] = tr * wi + ti * wr;
        }
        __syncthreads();
        cur ^= 1;
    }
    const float scale = (1.0f / 64.0f) * (1.0f / 16.0f);
    for (int k = threadIdx.x; k <= N2; k += 256) {
        int k2 = k & (N2 - 1), km = (N2 - k) & (N2 - 1);
        float yr = Sr[cur][k2], yi = Si[cur][k2];
        float zr = Sr[cur][km], zi = Si[cur][km];
        float Ar = 0.5f * (yr + zr), Ai = 0.5f * (yi - zi);
        float Br = 0.5f * (yi + zi), Bi = -0.5f * (yr - zr);
        float wr, wi;
        if (k < N2) { float2 w = tw[k]; wr = w.x; wi = w.y; }
        else { wr = -1.f; wi = 0.f; }
        float Xr = Ar + wr * Br - wi * Bi;
        float Xi = Ai + wr * Bi + wi * Br;
        atomicAdd(&mag[b * cBINS + k], sqrtf(Xr * Xr + Xi * Xi) * scale);
    }
}

// ---------------- RBF basis ----------------
__global__ __launch_bounds__(256) void k_basis(float* __restrict__ basis) {
    __shared__ float vals[cBINS];
    __shared__ float red[256];
    int band = blockIdx.x;
    float cb = (float)band / 15.0f;
    float inv_w = 15.0f / 1.5f;
    float local = 0.f;
    for (int k = threadIdx.x; k < cBINS; k += 256) {
        float f = (float)k / 2048.0f;
        float u = (f - cb) * inv_w;
        float v = expf(-0.5f * u * u);
        vals[k] = v;
        local += v;
    }
    red[threadIdx.x] = local;
    __syncthreads();
    for (int s = 128; s > 0; s >>= 1) {
        if (threadIdx.x < s) red[threadIdx.x] += red[threadIdx.x + s];
        __syncthreads();
    }
    float inv_sum = 1.0f / fmaxf(red[0], 1e-8f);
    for (int k = threadIdx.x; k < cBINS; k += 256)
        basis[band * cBINS + k] = vals[k] * inv_sum;
}

// ---------------- summary ----------------
__global__ __launch_bounds__(256) void k_summary(const float* __restrict__ mag,
                                                 const float* __restrict__ basis,
                                                 float* __restrict__ summary) {
    int b = blockIdx.x;
    float acc[cBANDS];
#pragma unroll
    for (int i = 0; i < cBANDS; i++) acc[i] = 0.f;
    for (int k = threadIdx.x; k < cBINS; k += 256) {
        float lm = log1pf(mag[b * cBINS + k]);
#pragma unroll
        for (int band = 0; band < cBANDS; band++) acc[band] += lm * basis[band * cBINS + k];
    }
    __shared__ float red[cBANDS][256];
#pragma unroll
    for (int band = 0; band < cBANDS; band++) red[band][threadIdx.x] = acc[band];
    __syncthreads();
    for (int s = 128; s > 0; s >>= 1) {
        if (threadIdx.x < s)
#pragma unroll
            for (int band = 0; band < cBANDS; band++)
                red[band][threadIdx.x] += red[band][threadIdx.x + s];
        __syncthreads();
    }
    if (threadIdx.x < cBANDS) summary[b * cBANDS + threadIdx.x] = red[threadIdx.x][0];
}

// ---------------- router: LN/proj/prototypes/softmax + routes + assign (cheap part only) ----------------
__global__ __launch_bounds__(64) void k_router(
    const float* __restrict__ summary, const float* __restrict__ ln_g,
    const float* __restrict__ ln_b, const float* __restrict__ proj_w,
    const float* __restrict__ prototypes, const float* __restrict__ route_lib,
    float* __restrict__ routes, float* __restrict__ assign_out) {
    int b = threadIdx.x;
    if (b >= cB) return;
    float s[cBANDS];
    float mean = 0.f;
#pragma unroll
    for (int i = 0; i < cBANDS; i++) { s[i] = summary[b * cBANDS + i]; mean += s[i]; }
    mean *= (1.0f / cBANDS);
    float var = 0.f;
#pragma unroll
    for (int i = 0; i < cBANDS; i++) { float d = s[i] - mean; var += d * d; }
    var *= (1.0f / cBANDS);
    float rstd = rsqrtf(var + cEPS);
#pragma unroll
    for (int i = 0; i < cBANDS; i++) s[i] = (s[i] - mean) * rstd * ln_g[i] + ln_b[i];
    float rs[cBANDS];
#pragma unroll
    for (int j = 0; j < cBANDS; j++) {
        float a = 0.f;
#pragma unroll
        for (int i = 0; i < cBANDS; i++) a += s[i] * proj_w[j * cBANDS + i];
        rs[j] = a;
    }
    float logits[cP];
    float mx = -1e30f;
#pragma unroll
    for (int p = 0; p < cP; p++) {
        float a = 0.f;
#pragma unroll
        for (int j = 0; j < cBANDS; j++) {
            float d = rs[j] - prototypes[p * cBANDS + j];
            a += d * d;
        }
        logits[p] = -(a * (1.0f / cBANDS)) * 4.0f;
        mx = fmaxf(mx, logits[p]);
    }
    float assign[cP];
    float denom = 0.f;
#pragma unroll
    for (int p = 0; p < cP; p++) { assign[p] = expf(logits[p] - mx); denom += assign[p]; }
    float invden = 1.0f / denom;
#pragma unroll
    for (int p = 0; p < cP; p++) {
        assign[p] *= invden;
        assign_out[b * cP + p] = assign[p];
    }
    for (int d = 0; d < cD; d++) {
        float r[cE];
        float rmx = -1e30f;
#pragma unroll
        for (int e = 0; e < cE; e++) {
            float a = 0.f;
#pragma unroll
            for (int p = 0; p < cP; p++) a += assign[p] * route_lib[(p * cD + d) * cE + e];
            r[e] = a;
            rmx = fmaxf(rmx, a);
        }
        float rden = 0.f;
#pragma unroll
        for (int e = 0; e < cE; e++) { r[e] = expf(r[e] - rmx); rden += r[e]; }
        float rinv = 1.0f / rden;
#pragma unroll
        for (int e = 0; e < cE; e++) routes[(b * cD + d) * cE + e] = r[e] * rinv;
    }
}

// ---------------- gains: one thread per (b, d, c), coalesced over gain_lib ----------------
__global__ __launch_bounds__(256) void k_gains(const float* __restrict__ assign,
                                               const float* __restrict__ gain_lib,
                                               float* __restrict__ gains) {
    int i = blockIdx.x * 256 + threadIdx.x;
    if (i >= cB * cD * cH) return;
    int b = i / (cD * cH);
    int dc = i % (cD * cH);            // d*cH + c
    float a = 0.f;
#pragma unroll
    for (int p = 0; p < cP; p++) a += assign[b * cP + p] * gain_lib[p * cD * cH + dc];
    gains[i] = 1.0f + 0.5f * tanhf(a);
}

// ---------------- effective 19-tap conv weights ----------------
__global__ __launch_bounds__(192) void k_weff(const float* __restrict__ ew_all,
                                              const float* __restrict__ routes,
                                              unsigned short* __restrict__ weff_g) {
    int bd = blockIdx.x;
    int d = bd % cD;
    int c = threadIdx.x;
    float rte[cE];
#pragma unroll
    for (int e = 0; e < cE; e++) rte[e] = routes[bd * cE + e];
    float acc[NTAP];
#pragma unroll
    for (int o = 0; o < NTAP; o++) acc[o] = 0.f;
#pragma unroll
    for (int e = 0; e < cE; e++) {
#pragma unroll
        for (int k = 0; k < cK; k++)
            acc[IDXT[e][k]] += rte[e] * ew_all[(((size_t)d * cE + e) * cH + c) * cK + k];
    }
    unsigned short* dst = weff_g + ((size_t)bd * cH + c) * 20;
#pragma unroll
    for (int o = 0; o < NTAP; o++) dst[o] = f2bf(acc[o]);
    dst[NTAP] = 0;
}

// ---------------- stem (writes bf16 z) ----------------
constexpr int STT = 256;
__global__ __launch_bounds__(256) void k_stem(const float* __restrict__ x,
                                              const float* __restrict__ stem_w,
                                              const float* __restrict__ bn_g,
                                              const float* __restrict__ bn_b,
                                              unsigned short* __restrict__ z,
                                              float* __restrict__ sums_out) {
    __shared__ float xs[cCIN][STT + 2];
    __shared__ float ws[cH * cCIN * 3];
    int blk = blockIdx.x;
    int b = blk / (cT / STT);
    int t0 = (blk % (cT / STT)) * STT;
    for (int i = threadIdx.x; i < cH * cCIN * 3; i += 256) ws[i] = stem_w[i];
    for (int i = threadIdx.x; i < cCIN * (STT + 2); i += 256) {
        int c = i / (STT + 2), tt = i % (STT + 2);
        int gt = t0 + tt - 1;
        xs[c][tt] = (gt >= 0 && gt < cT) ? x[((size_t)b * cCIN + c) * cT + gt] : 0.f;
    }
    __syncthreads();
    int tt = threadIdx.x;
    float xv[cCIN][3];
#pragma unroll
    for (int c = 0; c < cCIN; c++)
#pragma unroll
        for (int k = 0; k < 3; k++) xv[c][k] = xs[c][tt + k];
    int gt = t0 + tt;
    float bnrs = rsqrtf(1.0f + cEPS);
    float s = 0.f, q = 0.f;
    for (int h = 0; h < cH; h++) {
        const float* w = &ws[h * cCIN * 3];
        float acc = 0.f;
#pragma unroll
        for (int c = 0; c < cCIN; c++)
#pragma unroll
            for (int k = 0; k < 3; k++) acc += xv[c][k] * w[c * 3 + k];
        float v = acc * (bn_g[h] * bnrs) + bn_b[h];
        unsigned short rb = f2bf(gelu_exact(v));
        float res = bf2f(rb);
        z[((size_t)b * cH + h) * cT + gt] = rb;
        s += res; q += res * res;
    }
#pragma unroll
    for (int off = 32; off > 0; off >>= 1) { s += __shfl_down(s, off); q += __shfl_down(q, off); }
    if ((threadIdx.x & 63) == 0) {
        atomicAdd(&sums_out[b * 2], s);
        atomicAdd(&sums_out[b * 2 + 1], q);
    }
}

// ---------------- block part 1 (bf16 z stream) ----------------
__global__ __launch_bounds__(256, 2) void k_block1(
    const unsigned short* __restrict__ zin, unsigned short* __restrict__ zout,
    const float* __restrict__ sums_in, float* __restrict__ sums_out,
    const float* __restrict__ g1, const float* __restrict__ b1,
    const unsigned short* __restrict__ weff_g, const unsigned short* __restrict__ mwb,
    const float* __restrict__ mg, const float* __restrict__ mb,
    const float* __restrict__ gains, int d) {
    __shared__ unsigned short zn[cH][ZSTR];
    __shared__ unsigned short mxT[TT][200];
    int blk = xcd_swz(blockIdx.x);
    int b = blk / (cT / TT);
    int t0 = (blk % (cT / TT)) * TT;
    int tid = threadIdx.x;
    const float invN = 1.0f / (float)(cH * cT);
    float mean = sums_in[b * 2] * invN;
    float var = sums_in[b * 2 + 1] * invN - mean * mean;
    float rstd = rsqrtf(var + cEPS);
    // stage normalized tile with halo — fully unrolled; interior fast path (MLP: 21 8B loads)
    constexpr int S_ITERS = cH * 28 / 256;   // 21
    bool interior = (t0 >= HALO) && (t0 + TT + HALO <= cT);
    if (interior) {
#pragma unroll
        for (int it = 0; it < S_ITERS; it++) {
            int i = tid + it * 256;
            int c = i / 28, tt = (i % 28) * 4;
            int gt = t0 + tt - HALO;
            float gc = g1[c], bc = b1[c];
            ushort4 v = *reinterpret_cast<const ushort4*>(&zin[((size_t)b * cH + c) * cT + gt]);
            ushort4 pk;
            pk.x = f2bf((bf2f(v.x) - mean) * rstd * gc + bc);
            pk.y = f2bf((bf2f(v.y) - mean) * rstd * gc + bc);
            pk.z = f2bf((bf2f(v.z) - mean) * rstd * gc + bc);
            pk.w = f2bf((bf2f(v.w) - mean) * rstd * gc + bc);
            *reinterpret_cast<ushort4*>(&zn[c][tt]) = pk;
        }
    } else {
#pragma unroll
        for (int it = 0; it < S_ITERS; it++) {
            int i = tid + it * 256;
            int c = i / 28, tt = (i % 28) * 4;
            int gt = t0 + tt - HALO;
            float gc = g1[c], bc = b1[c];
            const unsigned short* zp = &zin[((size_t)b * cH + c) * cT];
            float n0 = (gt + 0 >= 0 && gt + 0 < cT) ? (bf2f(zp[gt + 0]) - mean) * rstd * gc + bc : 0.f;
            float n1 = (gt + 1 >= 0 && gt + 1 < cT) ? (bf2f(zp[gt + 1]) - mean) * rstd * gc + bc : 0.f;
            float n2 = (gt + 2 >= 0 && gt + 2 < cT) ? (bf2f(zp[gt + 2]) - mean) * rstd * gc + bc : 0.f;
            float n3 = (gt + 3 >= 0 && gt + 3 < cT) ? (bf2f(zp[gt + 3]) - mean) * rstd * gc + bc : 0.f;
            ushort4 pk;
            pk.x = f2bf(n0); pk.y = f2bf(n1); pk.z = f2bf(n2); pk.w = f2bf(n3);
            *reinterpret_cast<ushort4*>(&zn[c][tt]) = pk;
        }
    }
    // residual prefetch issued EARLY (T14)
    int lane = tid & 63, wid = tid >> 6;
    int lrow = lane & 15;
    int lk8 = (lane >> 4) << 3;
    int r0 = (lane >> 4) << 2;
    int mbase = wid * 48;
    float res[3][4][4];
#pragma unroll
    for (int mt = 0; mt < 3; mt++)
#pragma unroll
        for (int nt = 0; nt < 4; nt++)
#pragma unroll
            for (int r = 0; r < 4; r++)
                res[mt][nt][r] = bf2f(zin[((size_t)b * cH + mbase + mt * 16 + r0 + r) * cT +
                                         t0 + nt * 16 + lrow]);
    __syncthreads();
    // dwconv: lane owns one channel; window in registers, all-static indices
    if (tid < cH) {
        int c = tid;
        const unsigned short* wp = weff_g + ((size_t)(b * cD + d) * cH + c) * 20;
        float wv[NTAP];
#pragma unroll
        for (int o = 0; o < NTAP; o++) wv[o] = bf2f(wp[o]);
        float g = gains[((size_t)b * cD + d) * cH + c];
        float win[ZSTR];
#pragma unroll
        for (int v = 0; v < 14; v++) {
            bf16x8 w8 = *reinterpret_cast<const bf16x8*>(&zn[c][8 * v]);
#pragma unroll
            for (int u = 0; u < 8; u++) win[8 * v + u] = (float)w8[u];
        }
#pragma unroll
        for (int t = 0; t < TT; t++) {
            float a = 0.f;
#pragma unroll
            for (int o = 0; o < NTAP; o++)
                a = fmaf(wv[o], win[t + HALO + OFFS[o]], a);
            mxT[t][c] = f2bf(a * g);
        }
    }
    __syncthreads();
    // mix matmul: M=192, K=192, N=64
    f32x4 acc[3][4];
#pragma unroll
    for (int mt = 0; mt < 3; mt++)
#pragma unroll
        for (int nt = 0; nt < 4; nt++)
#pragma unroll
            for (int r = 0; r < 4; r++) acc[mt][nt][r] = 0.f;
#pragma unroll
    for (int kk = 0; kk < 6; kk++) {
        int k0 = kk * 32 + lk8;
        bf16x8 a0 = *reinterpret_cast<const bf16x8*>(&mwb[(size_t)(mbase + lrow) * cH + k0]);
        bf16x8 a1 = *reinterpret_cast<const bf16x8*>(&mwb[(size_t)(mbase + 16 + lrow) * cH + k0]);
        bf16x8 a2 = *reinterpret_cast<const bf16x8*>(&mwb[(size_t)(mbase + 32 + lrow) * cH + k0]);
#pragma unroll
        for (int nt = 0; nt < 4; nt++) {
            bf16x8 bf = *reinterpret_cast<const bf16x8*>(&mxT[nt * 16 + lrow][k0]);
            acc[0][nt] = __builtin_amdgcn_mfma_f32_16x16x32_bf16(a0, bf, acc[0][nt], 0, 0, 0);
            acc[1][nt] = __builtin_amdgcn_mfma_f32_16x16x32_bf16(a1, bf, acc[1][nt], 0, 0, 0);
            acc[2][nt] = __builtin_amdgcn_mfma_f32_16x16x32_bf16(a2, bf, acc[2][nt], 0, 0, 0);
        }
    }
    float bnrs = rsqrtf(1.0f + cEPS);
    float s = 0.f, q = 0.f;
#pragma unroll
    for (int mt = 0; mt < 3; mt++) {
#pragma unroll
        for (int nt = 0; nt < 4; nt++) {
#pragma unroll
            for (int r = 0; r < 4; r++) {
                int o = mbase + mt * 16 + r0 + r;
                int t = t0 + nt * 16 + lrow;
                size_t idx = ((size_t)b * cH + o) * cT + t;
                unsigned short vb = f2bf(res[mt][nt][r] +
                                         gelu_exact(acc[mt][nt][r] * (mg[o] * bnrs) + mb[o]));
                float val = bf2f(vb);
                zout[idx] = vb;
                s += val; q += val * val;
            }
        }
    }
#pragma unroll
    for (int off = 32; off > 0; off >>= 1) { s += __shfl_down(s, off); q += __shfl_down(q, off); }
    if (lane == 0) {
        atomicAdd(&sums_out[b * 2], s);
        atomicAdd(&sums_out[b * 2 + 1], q);
    }
}

// ---------------- block part 2: 256 threads, 2 barriers, full hT (R14 structure at proven regalloc) ----------------
// 4 waves each own 96 rows of w1 (acc1[6][4] = 96 VGPR); full hT written in one phase;
// w2 over full K=384. launch_bounds(256,2): VGPR cap 256 (R9/R12 proven no-spill regime).
__global__ __launch_bounds__(256, 2) void k_block2(
    unsigned short* __restrict__ z, const float* __restrict__ sums_in,
    float* __restrict__ sums_out,
    const float* __restrict__ g2, const float* __restrict__ b2,
    const unsigned short* __restrict__ w1b, const float* __restrict__ bb1,
    const unsigned short* __restrict__ w2b, const float* __restrict__ bb2) {
    __shared__ unsigned short znT[TT][200];   // 25.6K
    __shared__ unsigned short hT[TT][392];    // 50.2K, 784B rows (49x16B, odd slot stride)
    int blk = xcd_swz(blockIdx.x);
    int b = blk / (cT / TT);
    int t0 = (blk % (cT / TT)) * TT;
    const float invN = 1.0f / (float)(cH * cT);
    float mean = sums_in[b * 2] * invN;
    float var = sums_in[b * 2 + 1] * invN - mean * mean;
    float rstd = rsqrtf(var + cEPS);
    // staging — fully unrolled (12 8B loads per thread)
    constexpr int S_ITERS = cH * (TT / 4) / 256;  // 12
#pragma unroll
    for (int it = 0; it < S_ITERS; it++) {
        int i = threadIdx.x + it * 256;
        int c = i >> 4, t4 = (i & 15) << 2;
        ushort4 v = *reinterpret_cast<const ushort4*>(&z[((size_t)b * cH + c) * cT + t0 + t4]);
        float gc = g2[c], bc = b2[c];
        znT[t4 + 0][c] = f2bf((bf2f(v.x) - mean) * rstd * gc + bc);
        znT[t4 + 1][c] = f2bf((bf2f(v.y) - mean) * rstd * gc + bc);
        znT[t4 + 2][c] = f2bf((bf2f(v.z) - mean) * rstd * gc + bc);
        znT[t4 + 3][c] = f2bf((bf2f(v.w) - mean) * rstd * gc + bc);
    }
    int lane = threadIdx.x & 63, wid = threadIdx.x >> 6;   // wid 0..3
    int lrow = lane & 15;
    int lk8 = (lane >> 4) << 3;
    int r0 = (lane >> 4) << 2;
    int obase = wid * 48;
    // residual prefetch (T14) — consumed at the end
    float res[3][4][4];
#pragma unroll
    for (int mt = 0; mt < 3; mt++)
#pragma unroll
        for (int nt = 0; nt < 4; nt++)
#pragma unroll
            for (int r = 0; r < 4; r++)
                res[mt][nt][r] = bf2f(z[((size_t)b * cH + obase + mt * 16 + r0 + r) * cT +
                                        t0 + nt * 16 + lrow]);
    __syncthreads();   // A: znT ready
    // ---- w1: wave owns rows [wid*96, wid*96+96), all 64 t; acc1[6][4] ----
    int mb = wid * 96;
    f32x4 acc1[6][4];
#pragma unroll
    for (int g = 0; g < 6; g++) {
#pragma unroll
        for (int r = 0; r < 4; r++) {
            float bv = bb1[mb + g * 16 + r0 + r];
            acc1[g][0][r] = bv; acc1[g][1][r] = bv; acc1[g][2][r] = bv; acc1[g][3][r] = bv;
        }
    }
#pragma unroll
    for (int kk = 0; kk < 6; kk++) {
        int k0 = kk * 32 + lk8;
        bf16x8 af[6];
#pragma unroll
        for (int g = 0; g < 6; g++)
            af[g] = *reinterpret_cast<const bf16x8*>(&w1b[(size_t)(mb + g * 16 + lrow) * cH + k0]);
#pragma unroll
        for (int nt = 0; nt < 4; nt++) {
            bf16x8 bf = *reinterpret_cast<const bf16x8*>(&znT[nt * 16 + lrow][k0]);
#pragma unroll
            for (int g = 0; g < 6; g++)
                acc1[g][nt] = __builtin_amdgcn_mfma_f32_16x16x32_bf16(af[g], bf, acc1[g][nt], 0, 0, 0);
        }
    }
    // write full hT slice (cols = wave's 96 hidden rows)
#pragma unroll
    for (int g = 0; g < 6; g++) {
        int o0 = mb + g * 16 + r0;
#pragma unroll
        for (int nt = 0; nt < 4; nt++) {
            int t = nt * 16 + lrow;
            ushort4 pk;
            pk.x = f2bf(gelu_exact(acc1[g][nt][0]));
            pk.y = f2bf(gelu_exact(acc1[g][nt][1]));
            pk.z = f2bf(gelu_exact(acc1[g][nt][2]));
            pk.w = f2bf(gelu_exact(acc1[g][nt][3]));
            *reinterpret_cast<ushort4*>(&hT[t][o0]) = pk;
        }
    }
    __syncthreads();   // B: hT ready
    // ---- w2: K=384 full, wave owns 48 output rows, all 64 t ----
    f32x4 acc2[3][4];
#pragma unroll
    for (int mt = 0; mt < 3; mt++) {
#pragma unroll
        for (int r = 0; r < 4; r++) {
            float bv = bb2[obase + mt * 16 + r0 + r];
            acc2[mt][0][r] = bv; acc2[mt][1][r] = bv; acc2[mt][2][r] = bv; acc2[mt][3][r] = bv;
        }
    }
#pragma unroll
    for (int kk = 0; kk < 12; kk++) {
        int k0 = kk * 32 + lk8;
        bf16x8 a0 = *reinterpret_cast<const bf16x8*>(&w2b[(size_t)(obase + lrow) * cHM + k0]);
        bf16x8 a1 = *reinterpret_cast<const bf16x8*>(&w2b[(size_t)(obase + 16 + lrow) * cHM + k0]);
        bf16x8 a2 = *reinterpret_cast<const bf16x8*>(&w2b[(size_t)(obase + 32 + lrow) * cHM + k0]);
#pragma unroll
        for (int nt = 0; nt < 4; nt++) {
            bf16x8 bf = *reinterpret_cast<const bf16x8*>(&hT[nt * 16 + lrow][k0]);
            acc2[0][nt] = __builtin_amdgcn_mfma_f32_16x16x32_bf16(a0, bf, acc2[0][nt], 0, 0, 0);
            acc2[1][nt] = __builtin_amdgcn_mfma_f32_16x16x32_bf16(a1, bf, acc2[1][nt], 0, 0, 0);
            acc2[2][nt] = __builtin_amdgcn_mfma_f32_16x16x32_bf16(a2, bf, acc2[2][nt], 0, 0, 0);
        }
    }
    float s = 0.f, q = 0.f;
#pragma unroll
    for (int mt = 0; mt < 3; mt++) {
#pragma unroll
        for (int nt = 0; nt < 4; nt++) {
#pragma unroll
            for (int r = 0; r < 4; r++) {
                int o = obase + mt * 16 + r0 + r;
                int t = t0 + nt * 16 + lrow;
                size_t idx = ((size_t)b * cH + o) * cT + t;
                unsigned short vb = f2bf(res[mt][nt][r] + acc2[mt][nt][r]);
                float val = bf2f(vb);
                z[idx] = vb;
                s += val; q += val * val;
            }
        }
    }
#pragma unroll
    for (int off = 32; off > 0; off >>= 1) { s += __shfl_down(s, off); q += __shfl_down(q, off); }
    if (lane == 0) {
        atomicAdd(&sums_out[b * 2], s);
        atomicAdd(&sums_out[b * 2 + 1], q);
    }
}

// ---------------- global average pool (bf16 z) ----------------
__global__ __launch_bounds__(256) void k_pool(const unsigned short* __restrict__ z,
                                              float* __restrict__ pooled) {
    int bh = blockIdx.x;
    const unsigned short* zp = z + (size_t)bh * cT;
    float s = 0.f;
#pragma unroll
    for (int it = 0; it < 2; it++) {
        uint4 v = *reinterpret_cast<const uint4*>(&zp[(threadIdx.x + it * 256) * 8]);
        s += bflo(v.x) + bfhi(v.x) + bflo(v.y) + bfhi(v.y) +
             bflo(v.z) + bfhi(v.z) + bflo(v.w) + bfhi(v.w);
    }
    __shared__ float red[256];
    red[threadIdx.x] = s;
    __syncthreads();
    for (int st = 128; st > 0; st >>= 1) {
        if (threadIdx.x < st) red[threadIdx.x] += red[threadIdx.x + st];
        __syncthreads();
    }
    if (threadIdx.x == 0) pooled[bh] = red[0] * (1.0f / cT);
}

// ---------------- head ----------------
__global__ __launch_bounds__(256) void k_head(const float* __restrict__ pooled,
                                              const float* __restrict__ hw,
                                              const float* __restrict__ hb,
                                              float* __restrict__ out) {
    int i = blockIdx.x * 256 + threadIdx.x;
    if (i >= cB * cNCLS) return;
    int b = i / cNCLS, n = i % cNCLS;
    float acc = hb[n];
    const float* pw = pooled + b * cH;
    const float* wr = hw + n * cH;
    for (int h = 0; h < cH; h++) acc += pw[h] * wr[h];
    out[i] = acc;
}

extern "C" void kernel_launch(void* const* d_in, const int* in_sizes, int n_in,
                              void* d_out, int out_size, void* d_ws, size_t ws_size,
                              hipStream_t stream) {
    const float* x          = (const float*)d_in[0];
    const float* stem_w     = (const float*)d_in[1];
    const float* stem_bn_g  = (const float*)d_in[2];
    const float* stem_bn_b  = (const float*)d_in[3];
    const float* ln_g       = (const float*)d_in[4];
    const float* ln_b       = (const float*)d_in[5];
    const float* proj_w     = (const float*)d_in[6];
    const float* prototypes = (const float*)d_in[7];
    const float* route_lib  = (const float*)d_in[8];
    const float* gain_lib   = (const float*)d_in[9];
    const float* norm1_g    = (const float*)d_in[10];
    const float* norm1_b    = (const float*)d_in[11];
    const float* expert_w   = (const float*)d_in[12];
    const float* mix_w      = (const float*)d_in[13];
    const float* mix_bn_g   = (const float*)d_in[14];
    const float* mix_bn_b   = (const float*)d_in[15];
    const float* norm2_g    = (const float*)d_in[16];
    const float* norm2_b    = (const float*)d_in[17];
    const float* mlp_w1     = (const float*)d_in[18];
    const float* mlp_b1     = (const float*)d_in[19];
    const float* mlp_w2     = (const float*)d_in[20];
    const float* mlp_b2     = (const float*)d_in[21];
    const float* head_w     = (const float*)d_in[22];
    const float* head_b     = (const float*)d_in[23];

    float* ws = (float*)d_ws;
    size_t off = 0;
    const size_t ZN = (size_t)cB * cH * cT;
    unsigned short* zA = (unsigned short*)(ws + off); off += ZN / 2;   // bf16 z stream
    unsigned short* zB = (unsigned short*)(ws + off); off += ZN / 2;
    float* mag     = ws + off; off += (size_t)cB * cBINS;
    float* sums    = ws + off; off += 9 * cB * 2;
    float* basis   = ws + off; off += (size_t)cBANDS * cBINS;
    float* summary = ws + off; off += cB * cBANDS;
    float* routes  = ws + off; off += cB * cD * cE;
    float* assign  = ws + off; off += cB * cP;
    float* gains   = ws + off; off += (size_t)cB * cD * cH;
    float* pooled  = ws + off; off += cB * cH;
    float2* tw     = (float2*)(ws + off); off += 2 * (cT - 1) + 2;
    unsigned short* mixb = (unsigned short*)(ws + off); off += (size_t)cD * cH * cH / 2;
    unsigned short* w1b  = (unsigned short*)(ws + off); off += (size_t)cD * cHM * cH / 2;
    unsigned short* w2b  = (unsigned short*)(ws + off); off += (size_t)cD * cH * cHM / 2;
    unsigned short* weff = (unsigned short*)(ws + off); off += (size_t)cB * cD * cH * 20 / 2;

    int nz = cB * cBINS + 9 * cB * 2;
    k_zero<<<(nz + 255) / 256, 256, 0, stream>>>(mag, nz);

    k_cvt<<<(cD * cH * cH + 255) / 256, 256, 0, stream>>>(mix_w, mixb, cD * cH * cH);
    k_cvt<<<(cD * cHM * cH + 255) / 256, 256, 0, stream>>>(mlp_w1, w1b, cD * cHM * cH);
    k_cvt<<<(cD * cH * cHM + 255) / 256, 256, 0, stream>>>(mlp_w2, w2b, cD * cH * cHM);

    k_twiddle<<<12, 256, 0, stream>>>(tw);
    k_fft_mag<<<cB * cCIN, 256, 0, stream>>>(x, tw, mag);
    k_basis<<<cBANDS, 256, 0, stream>>>(basis);
    k_summary<<<cB, 256, 0, stream>>>(mag, basis, summary);
    k_router<<<1, 64, 0, stream>>>(summary, ln_g, ln_b, proj_w, prototypes,
                                   route_lib, routes, assign);
    k_gains<<<(cB * cD * cH + 255) / 256, 256, 0, stream>>>(assign, gain_lib, gains);
    k_weff<<<cB * cD, 192, 0, stream>>>(expert_w, routes, weff);

    k_stem<<<cB * (cT / STT), 256, 0, stream>>>(x, stem_w, stem_bn_g, stem_bn_b, zA,
                                                sums + 0 * cB * 2);

    unsigned short* zi = zA;
    unsigned short* zo = zB;
    for (int d = 0; d < cD; d++) {
        k_block1<<<cB * (cT / TT), 256, 0, stream>>>(
            zi, zo, sums + (size_t)(2 * d) * cB * 2, sums + (size_t)(2 * d + 1) * cB * 2,
            norm1_g + d * cH, norm1_b + d * cH,
            weff, mixb + (size_t)d * cH * cH,
            mix_bn_g + d * cH, mix_bn_b + d * cH, gains, d);
        k_block2<<<cB * (cT / TT), 256, 0, stream>>>(
            zo, sums + (size_t)(2 * d + 1) * cB * 2, sums + (size_t)(2 * d + 2) * cB * 2,
            norm2_g + d * cH, norm2_b + d * cH,
            w1b + (size_t)d * cHM * cH, mlp_b1 + d * cHM,
            w2b + (size_t)d * cH * cHM, mlp_b2 + d * cH);
        unsigned short* t = zi; zi = zo; zo = t;
    }

    k_pool<<<cB * cH, 256, 0, stream>>>(zi, pooled);
    k_head<<<(cB * cNCLS + 255) / 256, 256, 0, stream>>>(pooled, head_w, head_b,
                                                         (float*)d_out);
}

// Round 17
// 1030.284 us; speedup vs baseline: 1.2799x; 1.0113x over previous
//
#include <hip/hip_runtime.h>
#include <math.h>

constexpr int cB = 32, cCIN = 16, cT = 4096, cH = 192, cD = 4, cE = 4, cK = 7;
constexpr int cBANDS = 16, cP = 8, cHM = 384, cNCLS = 50, cBINS = 2049;
constexpr float cEPS = 1e-5f;
constexpr int TT = 64, HALO = 24;
constexpr int ZSTR = 112;      // zn row stride (u16): 224B, 16B-aligned
constexpr int NTAP = 19;
constexpr float INV_SQRT2 = 0.7071067811865475f;

typedef __bf16 bf16_t;
typedef bf16_t bf16x8 __attribute__((ext_vector_type(8)));
typedef float f32x4 __attribute__((ext_vector_type(4)));

// constexpr so unrolled indices FOLD (R5 lesson: __constant__ values can't fold -> scratch)
constexpr int OFFS[NTAP] = {-24,-16,-12,-8,-6,-4,-3,-2,-1,0,1,2,3,4,6,8,12,16,24};
constexpr int IDXT[cE][cK] = {
    {6, 7, 8, 9, 10, 11, 12},
    {4, 5, 7, 9, 11, 13, 14},
    {2, 3, 5, 9, 13, 15, 16},
    {0, 1, 3, 9, 15, 17, 18}};

__device__ __forceinline__ int xcd_swz(int bid) {
    // bijective for gridDim.x = 2048 (divisible by 8 XCDs)
    return (bid & 7) * 256 + (bid >> 3);
}

__device__ __forceinline__ float fast_erf(float x) {
    float ax = fabsf(x);
    float t = 1.0f / fmaf(0.3275911f, ax, 1.0f);
    float p = t * fmaf(t, fmaf(t, fmaf(t, fmaf(t, 1.061405429f, -1.453152027f),
                                       1.421413741f), -0.284496736f), 0.254829592f);
    float e = __expf(-ax * ax);
    float r = 1.0f - p * e;
    return copysignf(r, x);
}
__device__ __forceinline__ float gelu_exact(float v) {
    return 0.5f * v * (1.0f + fast_erf(v * INV_SQRT2));
}
// hardware bf16 convert (v_cvt_*_bf16_f32) via native cast — R17: replaces 4-op manual RNE
__device__ __forceinline__ unsigned short f2bf(float f) {
    union { __bf16 h; unsigned short u; } v;
    v.h = (__bf16)f;
    return v.u;
}
__device__ __forceinline__ float bf2f(unsigned short u) {
    union { unsigned u; float f; } v; v.u = ((unsigned)u) << 16;
    return v.f;
}
__device__ __forceinline__ float bflo(unsigned u) {
    union { unsigned u; float f; } v; v.u = u << 16;
    return v.f;
}
__device__ __forceinline__ float bfhi(unsigned u) {
    union { unsigned u; float f; } v; v.u = u & 0xFFFF0000u;
    return v.f;
}

// ---------------- zero scratch ----------------
__global__ __launch_bounds__(256) void k_zero(float* __restrict__ p, int n) {
    int i = blockIdx.x * 256 + threadIdx.x;
    if (i < n) p[i] = 0.f;
}

// ---------------- fp32 -> bf16 weight conversion ----------------
__global__ __launch_bounds__(256) void k_cvt(const float* __restrict__ src,
                                             unsigned short* __restrict__ dst, int n) {
    int i = blockIdx.x * 256 + threadIdx.x;
    if (i < n) dst[i] = f2bf(src[i]);
}

// ---------------- twiddle table ----------------
__global__ __launch_bounds__(256) void k_twiddle(float2* __restrict__ tw) {
    int ls = blockIdx.x;
    int n = cT >> ls;
    int cnt = n >> 1;
    int base = cT - (cT >> ls);
    for (int p = threadIdx.x; p < cnt; p += 256) {
        float ang = -6.283185307179586f * (float)p / (float)n;
        float sv, cv;
        sincosf(ang, &sv, &cv);
        tw[base + p] = make_float2(cv, sv);
    }
}

// ---------------- packed-real FFT magnitude: one block per (b, cin) ----------------
__global__ __launch_bounds__(256) void k_fft_mag(const float* __restrict__ x,
                                                 const float2* __restrict__ tw,
                                                 float* __restrict__ mag) {
    constexpr int N2 = cT / 2;   // 2048
    __shared__ float Sr[2][N2];
    __shared__ float Si[2][N2];
    int b = blockIdx.x / cCIN, c = blockIdx.x % cCIN;
    const float* xp = x + ((size_t)b * cCIN + c) * cT;
#pragma unroll
    for (int it = 0; it < N2 / 256; it++) {
        int t = threadIdx.x + it * 256;
        float2 v = *reinterpret_cast<const float2*>(&xp[2 * t]);
        Sr[0][t] = v.x; Si[0][t] = v.y;
    }
    __syncthreads();
    int cur = 0;
    for (int ls = 0; ls < 11; ls++) {
        int s = 1 << ls;
        int twb = cT - (cT >> (ls + 1));
#pragma unroll
        for (int it = 0; it < N2 / 512; it++) {
            int j = threadIdx.x + it * 256;
            int p = j >> ls;
            float2 w = tw[twb + p];
            float wr = w.x, wi = w.y;
            int ia = j, ib = j + N2 / 2;
            float ar = Sr[cur][ia], ai = Si[cur][ia];
            float br = Sr[cur][ib], bi = Si[cur][ib];
            int oa = j + (j & ~(s - 1));
            int ob = oa + s;
            Sr[cur ^ 1][oa] = ar + br;
            Si[cur ^ 1][oa] = ai + bi;
            float tr = ar - br, ti = ai - bi;
            Sr[cur ^ 1][ob] = tr * wr - ti * wi;
            Si[cur ^ 1][ob] = tr * wi + ti * wr;
        }
        __syncthreads();
        cur ^= 1;
    }
    const float scale = (1.0f / 64.0f) * (1.0f / 16.0f);
    for (int k = threadIdx.x; k <= N2; k += 256) {
        int k2 = k & (N2 - 1), km = (N2 - k) & (N2 - 1);
        float yr = Sr[cur][k2], yi = Si[cur][k2];
        float zr = Sr[cur][km], zi = Si[cur][km];
        float Ar = 0.5f * (yr + zr), Ai = 0.5f * (yi - zi);
        float Br = 0.5f * (yi + zi), Bi = -0.5f * (yr - zr);
        float wr, wi;
        if (k < N2) { float2 w = tw[k]; wr = w.x; wi = w.y; }
        else { wr = -1.f; wi = 0.f; }
        float Xr = Ar + wr * Br - wi * Bi;
        float Xi = Ai + wr * Bi + wi * Br;
        atomicAdd(&mag[b * cBINS + k], sqrtf(Xr * Xr + Xi * Xi) * scale);
    }
}

// ---------------- RBF basis ----------------
__global__ __launch_bounds__(256) void k_basis(float* __restrict__ basis) {
    __shared__ float vals[cBINS];
    __shared__ float red[256];
    int band = blockIdx.x;
    float cb = (float)band / 15.0f;
    float inv_w = 15.0f / 1.5f;
    float local = 0.f;
    for (int k = threadIdx.x; k < cBINS; k += 256) {
        float f = (float)k / 2048.0f;
        float u = (f - cb) * inv_w;
        float v = expf(-0.5f * u * u);
        vals[k] = v;
        local += v;
    }
    red[threadIdx.x] = local;
    __syncthreads();
    for (int s = 128; s > 0; s >>= 1) {
        if (threadIdx.x < s) red[threadIdx.x] += red[threadIdx.x + s];
        __syncthreads();
    }
    float inv_sum = 1.0f / fmaxf(red[0], 1e-8f);
    for (int k = threadIdx.x; k < cBINS; k += 256)
        basis[band * cBINS + k] = vals[k] * inv_sum;
}

// ---------------- summary ----------------
__global__ __launch_bounds__(256) void k_summary(const float* __restrict__ mag,
                                                 const float* __restrict__ basis,
                                                 float* __restrict__ summary) {
    int b = blockIdx.x;
    float acc[cBANDS];
#pragma unroll
    for (int i = 0; i < cBANDS; i++) acc[i] = 0.f;
    for (int k = threadIdx.x; k < cBINS; k += 256) {
        float lm = log1pf(mag[b * cBINS + k]);
#pragma unroll
        for (int band = 0; band < cBANDS; band++) acc[band] += lm * basis[band * cBINS + k];
    }
    __shared__ float red[cBANDS][256];
#pragma unroll
    for (int band = 0; band < cBANDS; band++) red[band][threadIdx.x] = acc[band];
    __syncthreads();
    for (int s = 128; s > 0; s >>= 1) {
        if (threadIdx.x < s)
#pragma unroll
            for (int band = 0; band < cBANDS; band++)
                red[band][threadIdx.x] += red[band][threadIdx.x + s];
        __syncthreads();
    }
    if (threadIdx.x < cBANDS) summary[b * cBANDS + threadIdx.x] = red[threadIdx.x][0];
}

// ---------------- router: LN/proj/prototypes/softmax + routes + assign (cheap part only) ----------------
__global__ __launch_bounds__(64) void k_router(
    const float* __restrict__ summary, const float* __restrict__ ln_g,
    const float* __restrict__ ln_b, const float* __restrict__ proj_w,
    const float* __restrict__ prototypes, const float* __restrict__ route_lib,
    float* __restrict__ routes, float* __restrict__ assign_out) {
    int b = threadIdx.x;
    if (b >= cB) return;
    float s[cBANDS];
    float mean = 0.f;
#pragma unroll
    for (int i = 0; i < cBANDS; i++) { s[i] = summary[b * cBANDS + i]; mean += s[i]; }
    mean *= (1.0f / cBANDS);
    float var = 0.f;
#pragma unroll
    for (int i = 0; i < cBANDS; i++) { float d = s[i] - mean; var += d * d; }
    var *= (1.0f / cBANDS);
    float rstd = rsqrtf(var + cEPS);
#pragma unroll
    for (int i = 0; i < cBANDS; i++) s[i] = (s[i] - mean) * rstd * ln_g[i] + ln_b[i];
    float rs[cBANDS];
#pragma unroll
    for (int j = 0; j < cBANDS; j++) {
        float a = 0.f;
#pragma unroll
        for (int i = 0; i < cBANDS; i++) a += s[i] * proj_w[j * cBANDS + i];
        rs[j] = a;
    }
    float logits[cP];
    float mx = -1e30f;
#pragma unroll
    for (int p = 0; p < cP; p++) {
        float a = 0.f;
#pragma unroll
        for (int j = 0; j < cBANDS; j++) {
            float d = rs[j] - prototypes[p * cBANDS + j];
            a += d * d;
        }
        logits[p] = -(a * (1.0f / cBANDS)) * 4.0f;
        mx = fmaxf(mx, logits[p]);
    }
    float assign[cP];
    float denom = 0.f;
#pragma unroll
    for (int p = 0; p < cP; p++) { assign[p] = expf(logits[p] - mx); denom += assign[p]; }
    float invden = 1.0f / denom;
#pragma unroll
    for (int p = 0; p < cP; p++) {
        assign[p] *= invden;
        assign_out[b * cP + p] = assign[p];
    }
    for (int d = 0; d < cD; d++) {
        float r[cE];
        float rmx = -1e30f;
#pragma unroll
        for (int e = 0; e < cE; e++) {
            float a = 0.f;
#pragma unroll
            for (int p = 0; p < cP; p++) a += assign[p] * route_lib[(p * cD + d) * cE + e];
            r[e] = a;
            rmx = fmaxf(rmx, a);
        }
        float rden = 0.f;
#pragma unroll
        for (int e = 0; e < cE; e++) { r[e] = expf(r[e] - rmx); rden += r[e]; }
        float rinv = 1.0f / rden;
#pragma unroll
        for (int e = 0; e < cE; e++) routes[(b * cD + d) * cE + e] = r[e] * rinv;
    }
}

// ---------------- gains: one thread per (b, d, c), coalesced over gain_lib ----------------
__global__ __launch_bounds__(256) void k_gains(const float* __restrict__ assign,
                                               const float* __restrict__ gain_lib,
                                               float* __restrict__ gains) {
    int i = blockIdx.x * 256 + threadIdx.x;
    if (i >= cB * cD * cH) return;
    int b = i / (cD * cH);
    int dc = i % (cD * cH);            // d*cH + c
    float a = 0.f;
#pragma unroll
    for (int p = 0; p < cP; p++) a += assign[b * cP + p] * gain_lib[p * cD * cH + dc];
    gains[i] = 1.0f + 0.5f * tanhf(a);
}

// ---------------- effective 19-tap conv weights ----------------
__global__ __launch_bounds__(192) void k_weff(const float* __restrict__ ew_all,
                                              const float* __restrict__ routes,
                                              unsigned short* __restrict__ weff_g) {
    int bd = blockIdx.x;
    int d = bd % cD;
    int c = threadIdx.x;
    float rte[cE];
#pragma unroll
    for (int e = 0; e < cE; e++) rte[e] = routes[bd * cE + e];
    float acc[NTAP];
#pragma unroll
    for (int o = 0; o < NTAP; o++) acc[o] = 0.f;
#pragma unroll
    for (int e = 0; e < cE; e++) {
#pragma unroll
        for (int k = 0; k < cK; k++)
            acc[IDXT[e][k]] += rte[e] * ew_all[(((size_t)d * cE + e) * cH + c) * cK + k];
    }
    unsigned short* dst = weff_g + ((size_t)bd * cH + c) * 20;
#pragma unroll
    for (int o = 0; o < NTAP; o++) dst[o] = f2bf(acc[o]);
    dst[NTAP] = 0;
}

// ---------------- stem (writes bf16 z) ----------------
constexpr int STT = 256;
__global__ __launch_bounds__(256) void k_stem(const float* __restrict__ x,
                                              const float* __restrict__ stem_w,
                                              const float* __restrict__ bn_g,
                                              const float* __restrict__ bn_b,
                                              unsigned short* __restrict__ z,
                                              float* __restrict__ sums_out) {
    __shared__ float xs[cCIN][STT + 2];
    __shared__ float ws[cH * cCIN * 3];
    int blk = blockIdx.x;
    int b = blk / (cT / STT);
    int t0 = (blk % (cT / STT)) * STT;
    for (int i = threadIdx.x; i < cH * cCIN * 3; i += 256) ws[i] = stem_w[i];
    for (int i = threadIdx.x; i < cCIN * (STT + 2); i += 256) {
        int c = i / (STT + 2), tt = i % (STT + 2);
        int gt = t0 + tt - 1;
        xs[c][tt] = (gt >= 0 && gt < cT) ? x[((size_t)b * cCIN + c) * cT + gt] : 0.f;
    }
    __syncthreads();
    int tt = threadIdx.x;
    float xv[cCIN][3];
#pragma unroll
    for (int c = 0; c < cCIN; c++)
#pragma unroll
        for (int k = 0; k < 3; k++) xv[c][k] = xs[c][tt + k];
    int gt = t0 + tt;
    float bnrs = rsqrtf(1.0f + cEPS);
    float s = 0.f, q = 0.f;
    for (int h = 0; h < cH; h++) {
        const float* w = &ws[h * cCIN * 3];
        float acc = 0.f;
#pragma unroll
        for (int c = 0; c < cCIN; c++)
#pragma unroll
            for (int k = 0; k < 3; k++) acc += xv[c][k] * w[c * 3 + k];
        float v = acc * (bn_g[h] * bnrs) + bn_b[h];
        unsigned short rb = f2bf(gelu_exact(v));
        float res = bf2f(rb);
        z[((size_t)b * cH + h) * cT + gt] = rb;
        s += res; q += res * res;
    }
#pragma unroll
    for (int off = 32; off > 0; off >>= 1) { s += __shfl_down(s, off); q += __shfl_down(q, off); }
    if ((threadIdx.x & 63) == 0) {
        atomicAdd(&sums_out[b * 2], s);
        atomicAdd(&sums_out[b * 2 + 1], q);
    }
}

// ---------------- block part 1 (bf16 z stream, folded GN affine) ----------------
__global__ __launch_bounds__(256, 2) void k_block1(
    const unsigned short* __restrict__ zin, unsigned short* __restrict__ zout,
    const float* __restrict__ sums_in, float* __restrict__ sums_out,
    const float* __restrict__ g1, const float* __restrict__ b1,
    const unsigned short* __restrict__ weff_g, const unsigned short* __restrict__ mwb,
    const float* __restrict__ mg, const float* __restrict__ mb,
    const float* __restrict__ gains, int d) {
    __shared__ unsigned short zn[cH][ZSTR];
    __shared__ unsigned short mxT[TT][200];
    int blk = xcd_swz(blockIdx.x);
    int b = blk / (cT / TT);
    int t0 = (blk % (cT / TT)) * TT;
    int tid = threadIdx.x;
    const float invN = 1.0f / (float)(cH * cT);
    float mean = sums_in[b * 2] * invN;
    float var = sums_in[b * 2 + 1] * invN - mean * mean;
    float rstd = rsqrtf(var + cEPS);
    // stage normalized tile with halo — folded affine: val = x*sc + bo (1 FMA/elem)
    constexpr int S_ITERS = cH * 28 / 256;   // 21
    bool interior = (t0 >= HALO) && (t0 + TT + HALO <= cT);
    if (interior) {
#pragma unroll
        for (int it = 0; it < S_ITERS; it++) {
            int i = tid + it * 256;
            int c = i / 28, tt = (i % 28) * 4;
            int gt = t0 + tt - HALO;
            float sc = g1[c] * rstd;
            float bo = fmaf(-mean, sc, b1[c]);
            ushort4 v = *reinterpret_cast<const ushort4*>(&zin[((size_t)b * cH + c) * cT + gt]);
            ushort4 pk;
            pk.x = f2bf(fmaf(bf2f(v.x), sc, bo));
            pk.y = f2bf(fmaf(bf2f(v.y), sc, bo));
            pk.z = f2bf(fmaf(bf2f(v.z), sc, bo));
            pk.w = f2bf(fmaf(bf2f(v.w), sc, bo));
            *reinterpret_cast<ushort4*>(&zn[c][tt]) = pk;
        }
    } else {
#pragma unroll
        for (int it = 0; it < S_ITERS; it++) {
            int i = tid + it * 256;
            int c = i / 28, tt = (i % 28) * 4;
            int gt = t0 + tt - HALO;
            float sc = g1[c] * rstd;
            float bo = fmaf(-mean, sc, b1[c]);
            const unsigned short* zp = &zin[((size_t)b * cH + c) * cT];
            float n0 = (gt + 0 >= 0 && gt + 0 < cT) ? fmaf(bf2f(zp[gt + 0]), sc, bo) : 0.f;
            float n1 = (gt + 1 >= 0 && gt + 1 < cT) ? fmaf(bf2f(zp[gt + 1]), sc, bo) : 0.f;
            float n2 = (gt + 2 >= 0 && gt + 2 < cT) ? fmaf(bf2f(zp[gt + 2]), sc, bo) : 0.f;
            float n3 = (gt + 3 >= 0 && gt + 3 < cT) ? fmaf(bf2f(zp[gt + 3]), sc, bo) : 0.f;
            ushort4 pk;
            pk.x = f2bf(n0); pk.y = f2bf(n1); pk.z = f2bf(n2); pk.w = f2bf(n3);
            *reinterpret_cast<ushort4*>(&zn[c][tt]) = pk;
        }
    }
    // residual prefetch issued EARLY (T14)
    int lane = tid & 63, wid = tid >> 6;
    int lrow = lane & 15;
    int lk8 = (lane >> 4) << 3;
    int r0 = (lane >> 4) << 2;
    int mbase = wid * 48;
    float res[3][4][4];
#pragma unroll
    for (int mt = 0; mt < 3; mt++)
#pragma unroll
        for (int nt = 0; nt < 4; nt++)
#pragma unroll
            for (int r = 0; r < 4; r++)
                res[mt][nt][r] = bf2f(zin[((size_t)b * cH + mbase + mt * 16 + r0 + r) * cT +
                                         t0 + nt * 16 + lrow]);
    __syncthreads();
    // dwconv: lane owns one channel; window in registers, all-static indices
    if (tid < cH) {
        int c = tid;
        const unsigned short* wp = weff_g + ((size_t)(b * cD + d) * cH + c) * 20;
        float wv[NTAP];
#pragma unroll
        for (int o = 0; o < NTAP; o++) wv[o] = bf2f(wp[o]);
        float g = gains[((size_t)b * cD + d) * cH + c];
        float win[ZSTR];
#pragma unroll
        for (int v = 0; v < 14; v++) {
            bf16x8 w8 = *reinterpret_cast<const bf16x8*>(&zn[c][8 * v]);
#pragma unroll
            for (int u = 0; u < 8; u++) win[8 * v + u] = (float)w8[u];
        }
#pragma unroll
        for (int t = 0; t < TT; t++) {
            float a = 0.f;
#pragma unroll
            for (int o = 0; o < NTAP; o++)
                a = fmaf(wv[o], win[t + HALO + OFFS[o]], a);
            mxT[t][c] = f2bf(a * g);
        }
    }
    __syncthreads();
    // mix matmul: M=192, K=192, N=64
    f32x4 acc[3][4];
#pragma unroll
    for (int mt = 0; mt < 3; mt++)
#pragma unroll
        for (int nt = 0; nt < 4; nt++)
#pragma unroll
            for (int r = 0; r < 4; r++) acc[mt][nt][r] = 0.f;
#pragma unroll
    for (int kk = 0; kk < 6; kk++) {
        int k0 = kk * 32 + lk8;
        bf16x8 a0 = *reinterpret_cast<const bf16x8*>(&mwb[(size_t)(mbase + lrow) * cH + k0]);
        bf16x8 a1 = *reinterpret_cast<const bf16x8*>(&mwb[(size_t)(mbase + 16 + lrow) * cH + k0]);
        bf16x8 a2 = *reinterpret_cast<const bf16x8*>(&mwb[(size_t)(mbase + 32 + lrow) * cH + k0]);
#pragma unroll
        for (int nt = 0; nt < 4; nt++) {
            bf16x8 bf = *reinterpret_cast<const bf16x8*>(&mxT[nt * 16 + lrow][k0]);
            acc[0][nt] = __builtin_amdgcn_mfma_f32_16x16x32_bf16(a0, bf, acc[0][nt], 0, 0, 0);
            acc[1][nt] = __builtin_amdgcn_mfma_f32_16x16x32_bf16(a1, bf, acc[1][nt], 0, 0, 0);
            acc[2][nt] = __builtin_amdgcn_mfma_f32_16x16x32_bf16(a2, bf, acc[2][nt], 0, 0, 0);
        }
    }
    float bnrs = rsqrtf(1.0f + cEPS);
    float s = 0.f, q = 0.f;
#pragma unroll
    for (int mt = 0; mt < 3; mt++) {
#pragma unroll
        for (int nt = 0; nt < 4; nt++) {
#pragma unroll
            for (int r = 0; r < 4; r++) {
                int o = mbase + mt * 16 + r0 + r;
                int t = t0 + nt * 16 + lrow;
                size_t idx = ((size_t)b * cH + o) * cT + t;
                unsigned short vb = f2bf(res[mt][nt][r] +
                                         gelu_exact(acc[mt][nt][r] * (mg[o] * bnrs) + mb[o]));
                float val = bf2f(vb);
                zout[idx] = vb;
                s += val; q += val * val;
            }
        }
    }
#pragma unroll
    for (int off = 32; off > 0; off >>= 1) { s += __shfl_down(s, off); q += __shfl_down(q, off); }
    if (lane == 0) {
        atomicAdd(&sums_out[b * 2], s);
        atomicAdd(&sums_out[b * 2 + 1], q);
    }
}

// ---------------- block part 2: 256 threads, 2 barriers, full hT, folded GN affine ----------------
__global__ __launch_bounds__(256, 2) void k_block2(
    unsigned short* __restrict__ z, const float* __restrict__ sums_in,
    float* __restrict__ sums_out,
    const float* __restrict__ g2, const float* __restrict__ b2,
    const unsigned short* __restrict__ w1b, const float* __restrict__ bb1,
    const unsigned short* __restrict__ w2b, const float* __restrict__ bb2) {
    __shared__ unsigned short znT[TT][200];   // 25.6K
    __shared__ unsigned short hT[TT][392];    // 50.2K, 784B rows (49x16B, odd slot stride)
    int blk = xcd_swz(blockIdx.x);
    int b = blk / (cT / TT);
    int t0 = (blk % (cT / TT)) * TT;
    const float invN = 1.0f / (float)(cH * cT);
    float mean = sums_in[b * 2] * invN;
    float var = sums_in[b * 2 + 1] * invN - mean * mean;
    float rstd = rsqrtf(var + cEPS);
    // staging — folded affine (1 FMA/elem), fully unrolled (12 8B loads per thread)
    constexpr int S_ITERS = cH * (TT / 4) / 256;  // 12
#pragma unroll
    for (int it = 0; it < S_ITERS; it++) {
        int i = threadIdx.x + it * 256;
        int c = i >> 4, t4 = (i & 15) << 2;
        ushort4 v = *reinterpret_cast<const ushort4*>(&z[((size_t)b * cH + c) * cT + t0 + t4]);
        float sc = g2[c] * rstd;
        float bo = fmaf(-mean, sc, b2[c]);
        znT[t4 + 0][c] = f2bf(fmaf(bf2f(v.x), sc, bo));
        znT[t4 + 1][c] = f2bf(fmaf(bf2f(v.y), sc, bo));
        znT[t4 + 2][c] = f2bf(fmaf(bf2f(v.z), sc, bo));
        znT[t4 + 3][c] = f2bf(fmaf(bf2f(v.w), sc, bo));
    }
    int lane = threadIdx.x & 63, wid = threadIdx.x >> 6;   // wid 0..3
    int lrow = lane & 15;
    int lk8 = (lane >> 4) << 3;
    int r0 = (lane >> 4) << 2;
    int obase = wid * 48;
    // residual prefetch (T14) — consumed at the end
    float res[3][4][4];
#pragma unroll
    for (int mt = 0; mt < 3; mt++)
#pragma unroll
        for (int nt = 0; nt < 4; nt++)
#pragma unroll
            for (int r = 0; r < 4; r++)
                res[mt][nt][r] = bf2f(z[((size_t)b * cH + obase + mt * 16 + r0 + r) * cT +
                                        t0 + nt * 16 + lrow]);
    __syncthreads();   // A: znT ready
    // ---- w1: wave owns rows [wid*96, wid*96+96), all 64 t; acc1[6][4] ----
    int mb = wid * 96;
    f32x4 acc1[6][4];
#pragma unroll
    for (int g = 0; g < 6; g++) {
#pragma unroll
        for (int r = 0; r < 4; r++) {
            float bv = bb1[mb + g * 16 + r0 + r];
            acc1[g][0][r] = bv; acc1[g][1][r] = bv; acc1[g][2][r] = bv; acc1[g][3][r] = bv;
        }
    }
#pragma unroll
    for (int kk = 0; kk < 6; kk++) {
        int k0 = kk * 32 + lk8;
        bf16x8 af[6];
#pragma unroll
        for (int g = 0; g < 6; g++)
            af[g] = *reinterpret_cast<const bf16x8*>(&w1b[(size_t)(mb + g * 16 + lrow) * cH + k0]);
#pragma unroll
        for (int nt = 0; nt < 4; nt++) {
            bf16x8 bf = *reinterpret_cast<const bf16x8*>(&znT[nt * 16 + lrow][k0]);
#pragma unroll
            for (int g = 0; g < 6; g++)
                acc1[g][nt] = __builtin_amdgcn_mfma_f32_16x16x32_bf16(af[g], bf, acc1[g][nt], 0, 0, 0);
        }
    }
    // write full hT slice (cols = wave's 96 hidden rows)
#pragma unroll
    for (int g = 0; g < 6; g++) {
        int o0 = mb + g * 16 + r0;
#pragma unroll
        for (int nt = 0; nt < 4; nt++) {
            int t = nt * 16 + lrow;
            ushort4 pk;
            pk.x = f2bf(gelu_exact(acc1[g][nt][0]));
            pk.y = f2bf(gelu_exact(acc1[g][nt][1]));
            pk.z = f2bf(gelu_exact(acc1[g][nt][2]));
            pk.w = f2bf(gelu_exact(acc1[g][nt][3]));
            *reinterpret_cast<ushort4*>(&hT[t][o0]) = pk;
        }
    }
    __syncthreads();   // B: hT ready
    // ---- w2: K=384 full, wave owns 48 output rows, all 64 t ----
    f32x4 acc2[3][4];
#pragma unroll
    for (int mt = 0; mt < 3; mt++) {
#pragma unroll
        for (int r = 0; r < 4; r++) {
            float bv = bb2[obase + mt * 16 + r0 + r];
            acc2[mt][0][r] = bv; acc2[mt][1][r] = bv; acc2[mt][2][r] = bv; acc2[mt][3][r] = bv;
        }
    }
#pragma unroll
    for (int kk = 0; kk < 12; kk++) {
        int k0 = kk * 32 + lk8;
        bf16x8 a0 = *reinterpret_cast<const bf16x8*>(&w2b[(size_t)(obase + lrow) * cHM + k0]);
        bf16x8 a1 = *reinterpret_cast<const bf16x8*>(&w2b[(size_t)(obase + 16 + lrow) * cHM + k0]);
        bf16x8 a2 = *reinterpret_cast<const bf16x8*>(&w2b[(size_t)(obase + 32 + lrow) * cHM + k0]);
#pragma unroll
        for (int nt = 0; nt < 4; nt++) {
            bf16x8 bf = *reinterpret_cast<const bf16x8*>(&hT[nt * 16 + lrow][k0]);
            acc2[0][nt] = __builtin_amdgcn_mfma_f32_16x16x32_bf16(a0, bf, acc2[0][nt], 0, 0, 0);
            acc2[1][nt] = __builtin_amdgcn_mfma_f32_16x16x32_bf16(a1, bf, acc2[1][nt], 0, 0, 0);
            acc2[2][nt] = __builtin_amdgcn_mfma_f32_16x16x32_bf16(a2, bf, acc2[2][nt], 0, 0, 0);
        }
    }
    float s = 0.f, q = 0.f;
#pragma unroll
    for (int mt = 0; mt < 3; mt++) {
#pragma unroll
        for (int nt = 0; nt < 4; nt++) {
#pragma unroll
            for (int r = 0; r < 4; r++) {
                int o = obase + mt * 16 + r0 + r;
                int t = t0 + nt * 16 + lrow;
                size_t idx = ((size_t)b * cH + o) * cT + t;
                unsigned short vb = f2bf(res[mt][nt][r] + acc2[mt][nt][r]);
                float val = bf2f(vb);
                z[idx] = vb;
                s += val; q += val * val;
            }
        }
    }
#pragma unroll
    for (int off = 32; off > 0; off >>= 1) { s += __shfl_down(s, off); q += __shfl_down(q, off); }
    if (lane == 0) {
        atomicAdd(&sums_out[b * 2], s);
        atomicAdd(&sums_out[b * 2 + 1], q);
    }
}

// ---------------- global average pool (bf16 z) ----------------
__global__ __launch_bounds__(256) void k_pool(const unsigned short* __restrict__ z,
                                              float* __restrict__ pooled) {
    int bh = blockIdx.x;
    const unsigned short* zp = z + (size_t)bh * cT;
    float s = 0.f;
#pragma unroll
    for (int it = 0; it < 2; it++) {
        uint4 v = *reinterpret_cast<const uint4*>(&zp[(threadIdx.x + it * 256) * 8]);
        s += bflo(v.x) + bfhi(v.x) + bflo(v.y) + bfhi(v.y) +
             bflo(v.z) + bfhi(v.z) + bflo(v.w) + bfhi(v.w);
    }
    __shared__ float red[256];
    red[threadIdx.x] = s;
    __syncthreads();
    for (int st = 128; st > 0; st >>= 1) {
        if (threadIdx.x < st) red[threadIdx.x] += red[threadIdx.x + st];
        __syncthreads();
    }
    if (threadIdx.x == 0) pooled[bh] = red[0] * (1.0f / cT);
}

// ---------------- head ----------------
__global__ __launch_bounds__(256) void k_head(const float* __restrict__ pooled,
                                              const float* __restrict__ hw,
                                              const float* __restrict__ hb,
                                              float* __restrict__ out) {
    int i = blockIdx.x * 256 + threadIdx.x;
    if (i >= cB * cNCLS) return;
    int b = i / cNCLS, n = i % cNCLS;
    float acc = hb[n];
    const float* pw = pooled + b * cH;
    const float* wr = hw + n * cH;
    for (int h = 0; h < cH; h++) acc += pw[h] * wr[h];
    out[i] = acc;
}

extern "C" void kernel_launch(void* const* d_in, const int* in_sizes, int n_in,
                              void* d_out, int out_size, void* d_ws, size_t ws_size,
                              hipStream_t stream) {
    const float* x          = (const float*)d_in[0];
    const float* stem_w     = (const float*)d_in[1];
    const float* stem_bn_g  = (const float*)d_in[2];
    const float* stem_bn_b  = (const float*)d_in[3];
    const float* ln_g       = (const float*)d_in[4];
    const float* ln_b       = (const float*)d_in[5];
    const float* proj_w     = (const float*)d_in[6];
    const float* prototypes = (const float*)d_in[7];
    const float* route_lib  = (const float*)d_in[8];
    const float* gain_lib   = (const float*)d_in[9];
    const float* norm1_g    = (const float*)d_in[10];
    const float* norm1_b    = (const float*)d_in[11];
    const float* expert_w   = (const float*)d_in[12];
    const float* mix_w      = (const float*)d_in[13];
    const float* mix_bn_g   = (const float*)d_in[14];
    const float* mix_bn_b   = (const float*)d_in[15];
    const float* norm2_g    = (const float*)d_in[16];
    const float* norm2_b    = (const float*)d_in[17];
    const float* mlp_w1     = (const float*)d_in[18];
    const float* mlp_b1     = (const float*)d_in[19];
    const float* mlp_w2     = (const float*)d_in[20];
    const float* mlp_b2     = (const float*)d_in[21];
    const float* head_w     = (const float*)d_in[22];
    const float* head_b     = (const float*)d_in[23];

    float* ws = (float*)d_ws;
    size_t off = 0;
    const size_t ZN = (size_t)cB * cH * cT;
    unsigned short* zA = (unsigned short*)(ws + off); off += ZN / 2;   // bf16 z stream
    unsigned short* zB = (unsigned short*)(ws + off); off += ZN / 2;
    float* mag     = ws + off; off += (size_t)cB * cBINS;
    float* sums    = ws + off; off += 9 * cB * 2;
    float* basis   = ws + off; off += (size_t)cBANDS * cBINS;
    float* summary = ws + off; off += cB * cBANDS;
    float* routes  = ws + off; off += cB * cD * cE;
    float* assign  = ws + off; off += cB * cP;
    float* gains   = ws + off; off += (size_t)cB * cD * cH;
    float* pooled  = ws + off; off += cB * cH;
    float2* tw     = (float2*)(ws + off); off += 2 * (cT - 1) + 2;
    unsigned short* mixb = (unsigned short*)(ws + off); off += (size_t)cD * cH * cH / 2;
    unsigned short* w1b  = (unsigned short*)(ws + off); off += (size_t)cD * cHM * cH / 2;
    unsigned short* w2b  = (unsigned short*)(ws + off); off += (size_t)cD * cH * cHM / 2;
    unsigned short* weff = (unsigned short*)(ws + off); off += (size_t)cB * cD * cH * 20 / 2;

    int nz = cB * cBINS + 9 * cB * 2;
    k_zero<<<(nz + 255) / 256, 256, 0, stream>>>(mag, nz);

    k_cvt<<<(cD * cH * cH + 255) / 256, 256, 0, stream>>>(mix_w, mixb, cD * cH * cH);
    k_cvt<<<(cD * cHM * cH + 255) / 256, 256, 0, stream>>>(mlp_w1, w1b, cD * cHM * cH);
    k_cvt<<<(cD * cH * cHM + 255) / 256, 256, 0, stream>>>(mlp_w2, w2b, cD * cH * cHM);

    k_twiddle<<<12, 256, 0, stream>>>(tw);
    k_fft_mag<<<cB * cCIN, 256, 0, stream>>>(x, tw, mag);
    k_basis<<<cBANDS, 256, 0, stream>>>(basis);
    k_summary<<<cB, 256, 0, stream>>>(mag, basis, summary);
    k_router<<<1, 64, 0, stream>>>(summary, ln_g, ln_b, proj_w, prototypes,
                                   route_lib, routes, assign);
    k_gains<<<(cB * cD * cH + 255) / 256, 256, 0, stream>>>(assign, gain_lib, gains);
    k_weff<<<cB * cD, 192, 0, stream>>>(expert_w, routes, weff);

    k_stem<<<cB * (cT / STT), 256, 0, stream>>>(x, stem_w, stem_bn_g, stem_bn_b, zA,
                                                sums + 0 * cB * 2);

    unsigned short* zi = zA;
    unsigned short* zo = zB;
    for (int d = 0; d < cD; d++) {
        k_block1<<<cB * (cT / TT), 256, 0, stream>>>(
            zi, zo, sums + (size_t)(2 * d) * cB * 2, sums + (size_t)(2 * d + 1) * cB * 2,
            norm1_g + d * cH, norm1_b + d * cH,
            weff, mixb + (size_t)d * cH * cH,
            mix_bn_g + d * cH, mix_bn_b + d * cH, gains, d);
        k_block2<<<cB * (cT / TT), 256, 0, stream>>>(
            zo, sums + (size_t)(2 * d + 1) * cB * 2, sums + (size_t)(2 * d + 2) * cB * 2,
            norm2_g + d * cH, norm2_b + d * cH,
            w1b + (size_t)d * cHM * cH, mlp_b1 + d * cHM,
            w2b + (size_t)d * cH * cHM, mlp_b2 + d * cH);
        unsigned short* t = zi; zi = zo; zo = t;
    }

    k_pool<<<cB * cH, 256, 0, stream>>>(zi, pooled);
    k_head<<<(cB * cNCLS + 255) / 256, 256, 0, stream>>>(pooled, head_w, head_b,
                                                         (float*)d_out);
}